// Round 5
// baseline (303.255 us; speedup 1.0000x reference)
//
#include <hip/hip_runtime.h>
#include <hip/hip_bf16.h>

// CSMultiHeadAttention. B=8, S=3072 (3x1024), E=512, H=8, d=64.
// fp32 I/O, bf16 workspace, fp32 MFMA accumulate.
// R5: attn 512 threads / 8 waves / 256 q rows; Q pre-scaled by SM_SCALE*log2e.
// R7/R8/R9: attn P-path in-register (permlane 4x4 transpose, VERIFIED R4 bench:
//   absmax 4.9e-4), pack2r packing (cvt_pk has different rounding -> fails),
//   Ps LDS deleted, T5 setprio around attn MFMA clusters.
// R10 (this round): T3 minimum 2-phase on all three tiled kernels.
//   R4 counters: qkv MfmaUtil 20.6%/VALU 17.9%/HBM 31% -> serialization-bound;
//   reg pressure (124 VGPR + 64 AGPR -> 2 blocks/CU) means no cross-block
//   overlap masks the serial stage->drain->compute. Fix: LDS double-buffer,
//   STAGE(t+1) issued BEFORE compute(t), ONE __syncthreads() per iter (its
//   implicit vmcnt(0) completes the prefetch AND protects the swap).
//   qkv/proj LDS 32->64KB (still reg-limited 2 blocks/CU), attn 16->32KB.
// MFMA 16x16x32 bf16. A/B frag: [m|n = lane&15][k = (lane>>4)*8 + j].
// C/D: col = lane&15, row = (lane>>4)*4 + reg.
// GEMM LDS tiles XOR-swizzled (block kb ^ (row&7)): free 2-way banks AND
// matches global_load_lds lane-contiguous destination.

typedef __attribute__((ext_vector_type(8))) short short8v;     // 8 bf16 (4 VGPR)
typedef __attribute__((ext_vector_type(4))) float float4v;
typedef __attribute__((ext_vector_type(4))) unsigned short ushort4v;
typedef __attribute__((ext_vector_type(4))) unsigned int uint4v;

#define CHUNKS 3
#define BATCH 8
#define SEQ 3072
#define EMB 512
#define NH 8
#define HD 64
#define NCK 1024
#define MTOT (BATCH*SEQ)                      // 24576
#define QKV_ELEMS (CHUNKS*BATCH*NH*NCK*HD)    // 12582912 (== x elem count)
#define WELEMS (CHUNKS*EMB*EMB)               // 786432 per weight tensor
// 1/sqrt(512) * log2(e): softmax exp folded to exp2
#define QSCALE 0.06375872465f

__device__ __forceinline__ unsigned short f2b(float f) {
  union { float f; unsigned int i; } x; x.f = f;
  unsigned int r = x.i + 0x7FFFu + ((x.i >> 16) & 1u);  // RNE
  return (unsigned short)(r >> 16);
}
// pack two fp32 -> two bf16 (round-half-up) in 3 VALU via v_perm
__device__ __forceinline__ unsigned int pack2r(float a, float b) {
  union { float f; unsigned int u; } xa, xb; xa.f = a; xb.f = b;
  return __builtin_amdgcn_perm(xb.u + 0x8000u, xa.u + 0x8000u, 0x07060302u);
}
__device__ __forceinline__ void gld_lds16(const unsigned short* g, unsigned short* l) {
  __builtin_amdgcn_global_load_lds(
      (const __attribute__((address_space(1))) unsigned int*)g,
      (__attribute__((address_space(3))) unsigned int*)l, 16, 0, 0);
}
#define MFMA(a, b, c) __builtin_amdgcn_mfma_f32_16x16x32_bf16(a, b, c, 0, 0, 0)

// ---------------- fp32 -> bf16 conversion (streaming) ----------------
__global__ __launch_bounds__(256) void conv_x(
    const float* __restrict__ src, unsigned short* __restrict__ dst)
{
  size_t i = ((size_t)blockIdx.x * 256 + threadIdx.x) * 8;  // grid exactly covers
  float4 a = *(const float4*)&src[i];
  float4 b = *(const float4*)&src[i + 4];
  uint4v p;
  p[0] = pack2r(a.x, a.y); p[1] = pack2r(a.z, a.w);
  p[2] = pack2r(b.x, b.y); p[3] = pack2r(b.z, b.w);
  *(uint4v*)&dst[i] = p;
}

__global__ __launch_bounds__(256) void conv_w(
    const float* __restrict__ s0, const float* __restrict__ s1,
    const float* __restrict__ s2, const float* __restrict__ s3,
    unsigned short* __restrict__ dst)
{
  const int z = blockIdx.y;
  const float* s = (z == 0) ? s0 : (z == 1) ? s1 : (z == 2) ? s2 : s3;
  size_t i = ((size_t)blockIdx.x * 256 + threadIdx.x) * 8;
  float4 a = *(const float4*)&s[i];
  float4 b = *(const float4*)&s[i + 4];
  uint4v p;
  p[0] = pack2r(a.x, a.y); p[1] = pack2r(a.z, a.w);
  p[2] = pack2r(b.x, b.y); p[3] = pack2r(b.z, b.w);
  *(uint4v*)&dst[(size_t)z * WELEMS + i] = p;
}

// ---------------- QKV projection ----------------
// 128x128 tile, BK=64, 4 waves; wave w: x-rows xo=(w&1)*64, f-cols fo=(w>>1)*64.
// Double-buffered LDS (T3 2-phase): STAGE(k+64) issued before compute(k);
// one __syncthreads() per K-step (implicit vmcnt(0) completes the prefetch).
// z<=1 (Q,K): D = W·X^T -> [f][token] -> packed b64 stores along d into [n][d].
//             Q is additionally scaled by QSCALE (softmax scale * log2e).
// z==2 (V):   D = X·W^T -> [token][f] -> packed b64 stores along n into [d][n].
#define QKV_STAGE(buf, k0v) do {                                               \
  _Pragma("unroll")                                                            \
  for (int s = 0; s < 4; ++s) {                                                \
    int rbase = w * 32 + s * 8;                                                \
    int r = rbase + sr;                                                        \
    int kb_g = kbl ^ sr;                                                       \
    gld_lds16(&Ag[(size_t)(row0 + r) * EMB + (k0v) + kb_g * 8],                \
              &As[buf][rbase * 64]);                                           \
    gld_lds16(&W [(size_t)(col0 + r) * EMB + (k0v) + kb_g * 8],                \
              &Bs[buf][rbase * 64]);                                           \
  }                                                                            \
} while (0)

__global__ __launch_bounds__(256) void qkv_gemm(
    const unsigned short* __restrict__ xb, const unsigned short* __restrict__ Wb,
    const float* __restrict__ bq, const float* __restrict__ bk,
    const float* __restrict__ bv,
    unsigned short* __restrict__ qt, unsigned short* __restrict__ kt,
    unsigned short* __restrict__ vt)
{
  const int tid = threadIdx.x;
  const int w = tid >> 6, l = tid & 63;
  const int ln = l & 15, qu = l >> 4;
  const int sr = l >> 3, kbl = l & 7;
  const int row0 = blockIdx.x * 128;
  const int col0 = blockIdx.y * 128;
  const int z = blockIdx.z;
  const int bglob = row0 / SEQ;
  const int c = (row0 % SEQ) / NCK;
  const int n0 = row0 % NCK;
  const unsigned short* Ag = xb;
  const unsigned short* W = Wb + (size_t)z * WELEMS + c * EMB * EMB;
  const float* bias = (z == 0 ? bq : (z == 1 ? bk : bv)) + c * EMB;
  const float oscale = (z == 0) ? QSCALE : 1.0f;

  __shared__ unsigned short As[2][128 * 64];   // x-tile, swizzled, dbuf
  __shared__ unsigned short Bs[2][128 * 64];   // W-tile, swizzled, dbuf

  const int xo = (w & 1) * 64, fo = (w >> 1) * 64;

  float4v acc[4][4];
#pragma unroll
  for (int i = 0; i < 4; ++i)
#pragma unroll
    for (int j = 0; j < 4; ++j) acc[i][j] = (float4v){0.f, 0.f, 0.f, 0.f};

  QKV_STAGE(0, 0);
  __syncthreads();
  int cur = 0;
  for (int k0 = 0; k0 < EMB; k0 += 64) {
    if (k0 + 64 < EMB) QKV_STAGE(cur ^ 1, k0 + 64);
#pragma unroll
    for (int ks = 0; ks < 2; ++ks) {
      short8v xf[4], wf[4];
#pragma unroll
      for (int i = 0; i < 4; ++i) {
        int rx = xo + 16 * i + ln;
        xf[i] = *(const short8v*)&As[cur][rx * 64 + (((ks * 4 + qu) ^ (rx & 7)) * 8)];
        int rw = fo + 16 * i + ln;
        wf[i] = *(const short8v*)&Bs[cur][rw * 64 + (((ks * 4 + qu) ^ (rw & 7)) * 8)];
      }
      if (z <= 1) {
#pragma unroll
        for (int i = 0; i < 4; ++i)
#pragma unroll
          for (int j = 0; j < 4; ++j) acc[i][j] = MFMA(wf[j], xf[i], acc[i][j]);
      } else {
#pragma unroll
        for (int i = 0; i < 4; ++i)
#pragma unroll
          for (int j = 0; j < 4; ++j) acc[i][j] = MFMA(xf[i], wf[j], acc[i][j]);
      }
    }
    __syncthreads();   // vmcnt(0): prefetch complete; all waves done with buf[cur]
    cur ^= 1;
  }

  if (z <= 1) {
    unsigned short* outp = (z == 0) ? qt : kt;
#pragma unroll
    for (int j = 0; j < 4; ++j) {            // f (M side)
      int f0 = col0 + fo + 16 * j + 4 * qu;  // + r
      float4 b4 = *(const float4*)&bias[f0];
      int hh = f0 >> 6, dd0 = f0 & 63;
      size_t base = ((size_t)((c * 8 + bglob) * 8 + hh)) << 16;
#pragma unroll
      for (int i = 0; i < 4; ++i) {          // token (N side)
        int n = n0 + xo + 16 * i + ln;
        ushort4v p;
#pragma unroll
        for (int r = 0; r < 4; ++r)
          p[r] = f2b((acc[i][j][r] + ((const float*)&b4)[r]) * oscale);
        *(ushort4v*)&outp[base + (size_t)n * 64 + dd0] = p;
      }
    }
  } else {
#pragma unroll
    for (int i = 0; i < 4; ++i) {            // token (M side)
      int nn0 = n0 + xo + 16 * i + 4 * qu;   // + r
#pragma unroll
      for (int j = 0; j < 4; ++j) {          // f (N side)
        int f = col0 + fo + 16 * j + ln;
        int hh = f >> 6, dd = f & 63;
        float bvv = bias[f];
        size_t base = ((size_t)((c * 8 + bglob) * 8 + hh)) << 16;
        ushort4v p;
#pragma unroll
        for (int r = 0; r < 4; ++r) p[r] = f2b(acc[i][j][r] + bvv);
        *(ushort4v*)&vt[base + (size_t)dd * 1024 + nn0] = p;
      }
    }
  }
}

// ---------------- Attention (flash, MFMA) ----------------
// 512 threads / 8 waves / 256 q rows per block; 4 q-blocks per head.
// Grid bid = qb*192 + head -> same-head blocks on one XCD (bid%8 const).
// K/V tiles double-buffered (T3 2-phase): STAGE(t+1) before compute(t),
// one __syncthreads() per tile.
// Per 64-key tile: S^T = K·Q^T (16 MFMA/wave); per 32-key half: exp2 ->
// pack2r -> permlane 4x4 transpose -> denominator(ones-MFMA) + O^T += V^T·P^T.
// Q is pre-scaled by 1/sqrt(512)*log2e in qkv -> raw v_exp_f32 here.
// setprio(1) wraps MFMA clusters (T5).
//
// P redistribution derivation: S^T C/D gives lane(ln,qu) the values
// S[q=ln][key=16*mt+4*qu+r]. PV B-frag needs lane(ln,qu) = P[q=ln][key=8*qu+j].
// Bit view: value with key bits (k4,k3,k2,k1) sits at source {mh=k4, l5=k3,
// l4=k2, p=k1}; target needs {l5=k4, l4=k3, word=(k2,k1)}. Realized by:
//   permlane32_swap(m00,m10); permlane32_swap(m01,m11);   // l5 <-> mh
//   permlane16_swap(m00,m10); permlane16_swap(m01,m11);   // l4 <-> old l5
// frag words = [m00, m01, m10, m11].  (VERIFIED on HW, R4: absmax 4.9e-4.)
#define ATTN_STAGE(buf, kt0v) do {                                             \
  int r = w * 8;                                                               \
  gld_lds16(&Kg[(size_t)((kt0v) + r + sr) * 64 + ((kbl ^ sr) * 8)],            \
            &Ks[buf][r * 64]);                                                 \
  gld_lds16(&Vg[(size_t)(r + sr) * 1024 + (kt0v) + ((kbl ^ sr) * 8)],          \
            &Vs[buf][r * 64]);                                                 \
} while (0)

__global__ __launch_bounds__(512) void attn_kernel(
    const unsigned short* __restrict__ qt,
    const unsigned short* __restrict__ kt,
    const unsigned short* __restrict__ vt,
    unsigned short* __restrict__ attnb)
{
  const int tid = threadIdx.x;
  const int w = tid >> 6, l = tid & 63;
  const int ln = l & 15, qu = l >> 4;
  const int sr = l >> 3, kbl = l & 7;
  const int bid = blockIdx.x;
  const int hd = bid % 192;                  // (co,b,h)
  const int q0 = (bid / 192) * 256;
  const int co = hd >> 6;
  const int b  = (hd >> 3) & 7;
  const int h  = hd & 7;
  const int cq = (co + 1) % 3, ckv = (co + 2) % 3;
  const unsigned short* Qg = qt + ((size_t)((cq  * 8 + b) * 8 + h) << 16);
  const unsigned short* Kg = kt + ((size_t)((ckv * 8 + b) * 8 + h) << 16);
  const unsigned short* Vg = vt + ((size_t)((ckv * 8 + b) * 8 + h) << 16);

  __shared__ unsigned short Ks[2][64 * 64];  // [key][d] swizzled, dbuf, 16KB
  __shared__ unsigned short Vs[2][64 * 64];  // [d][key] swizzled, dbuf, 16KB

  short8v qf[2][2];
#pragma unroll
  for (int nt = 0; nt < 2; ++nt)
#pragma unroll
    for (int ks = 0; ks < 2; ++ks)
      qf[nt][ks] = *(const short8v*)&Qg[(size_t)(q0 + w * 32 + nt * 16 + ln) * 64 + ks * 32 + qu * 8];

  short8v onesf;
#pragma unroll
  for (int i = 0; i < 8; ++i) onesf[i] = (short)0x3F80;   // bf16 1.0

  float4v acc_o[4][2];
#pragma unroll
  for (int i = 0; i < 4; ++i)
#pragma unroll
    for (int j = 0; j < 2; ++j) acc_o[i][j] = (float4v){0.f, 0.f, 0.f, 0.f};
  float4v acc_l[2];
  acc_l[0] = (float4v){0.f, 0.f, 0.f, 0.f};
  acc_l[1] = (float4v){0.f, 0.f, 0.f, 0.f};

  ATTN_STAGE(0, 0);
  __syncthreads();
  int cur = 0;
  for (int kt0 = 0; kt0 < NCK; kt0 += 64) {
    if (kt0 + 64 < NCK) ATTN_STAGE(cur ^ 1, kt0 + 64);

    // S-phase: S^T[key][q]
    float4v sacc[4][2];
#pragma unroll
    for (int mt = 0; mt < 4; ++mt)
#pragma unroll
      for (int nt = 0; nt < 2; ++nt) sacc[mt][nt] = (float4v){0.f, 0.f, 0.f, 0.f};
    __builtin_amdgcn_s_setprio(1);
#pragma unroll
    for (int ks = 0; ks < 2; ++ks) {
#pragma unroll
      for (int mt = 0; mt < 4; ++mt) {
        int key = 16 * mt + ln;
        short8v kf = *(const short8v*)&Ks[cur][key * 64 + (((ks * 4 + qu) ^ (key & 7)) * 8)];
#pragma unroll
        for (int nt = 0; nt < 2; ++nt)
          sacc[mt][nt] = MFMA(kf, qf[nt][ks], sacc[mt][nt]);
      }
    }
    __builtin_amdgcn_s_setprio(0);

    // per 32-key half: exp2 -> pack2r -> permlane transpose -> denom + PV
#pragma unroll
    for (int ks2 = 0; ks2 < 2; ++ks2) {
      short8v pf[2];
#pragma unroll
      for (int nt = 0; nt < 2; ++nt) {
        float4v s0v = sacc[2 * ks2][nt];      // mh=0: keys 16*2ks2 + 4qu + r
        float4v s1v = sacc[2 * ks2 + 1][nt];  // mh=1: keys 16*(2ks2+1) + 4qu + r
        float a0 = __builtin_amdgcn_exp2f(s0v[0]);
        float a1 = __builtin_amdgcn_exp2f(s0v[1]);
        float a2 = __builtin_amdgcn_exp2f(s0v[2]);
        float a3 = __builtin_amdgcn_exp2f(s0v[3]);
        float b0 = __builtin_amdgcn_exp2f(s1v[0]);
        float b1 = __builtin_amdgcn_exp2f(s1v[1]);
        float b2 = __builtin_amdgcn_exp2f(s1v[2]);
        float b3 = __builtin_amdgcn_exp2f(s1v[3]);
        unsigned int m00 = pack2r(a0, a1);    // (mh0,p0)
        unsigned int m01 = pack2r(a2, a3);    // (mh0,p1)
        unsigned int m10 = pack2r(b0, b1);    // (mh1,p0)
        unsigned int m11 = pack2r(b2, b3);    // (mh1,p1)
        asm("v_permlane32_swap_b32 %0, %1" : "+v"(m00), "+v"(m10));
        asm("v_permlane32_swap_b32 %0, %1" : "+v"(m01), "+v"(m11));
        asm("v_permlane16_swap_b32 %0, %1" : "+v"(m00), "+v"(m10));
        asm("v_permlane16_swap_b32 %0, %1" : "+v"(m01), "+v"(m11));
        uint4v t; t[0] = m00; t[1] = m01; t[2] = m10; t[3] = m11;
        pf[nt] = __builtin_bit_cast(short8v, t);
      }
      __builtin_amdgcn_s_setprio(1);
#pragma unroll
      for (int nt = 0; nt < 2; ++nt)
        acc_l[nt] = MFMA(onesf, pf[nt], acc_l[nt]);   // row-sum of P
#pragma unroll
      for (int mt2 = 0; mt2 < 4; ++mt2) {
        int dd = 16 * mt2 + ln;
        short8v vf = *(const short8v*)&Vs[cur][dd * 64 + (((ks2 * 4 + qu) ^ (dd & 7)) * 8)];
#pragma unroll
        for (int nt = 0; nt < 2; ++nt)
          acc_o[mt2][nt] = MFMA(vf, pf[nt], acc_o[mt2][nt]);
      }
      __builtin_amdgcn_s_setprio(0);
    }

    __syncthreads();   // vmcnt(0): prefetch done; all waves done with buf[cur]
    cur ^= 1;
  }

  float inv[2];
  inv[0] = 1.0f / acc_l[0][0];
  inv[1] = 1.0f / acc_l[1][0];
  unsigned short* Og = attnb + (size_t)((co * 8 + b)) * NCK * EMB + h * HD;
#pragma unroll
  for (int mt = 0; mt < 4; ++mt) {
    int dd0 = 16 * mt + 4 * qu;
#pragma unroll
    for (int nt = 0; nt < 2; ++nt) {
      int q_glob = q0 + w * 32 + nt * 16 + ln;
      ushort4v p;
#pragma unroll
      for (int r = 0; r < 4; ++r) p[r] = f2b(acc_o[mt][nt][r] * inv[nt]);
      *(ushort4v*)&Og[(size_t)q_glob * EMB + dd0] = p;
    }
  }
}

// ---------------- Output projection ----------------
// A = attnb (bf16), B = Wp_bf (bf16): both via global_load_lds, dbuf 2-phase.
// D = Wp·A^T -> [f][token]; fp32 float4 stores.
__global__ __launch_bounds__(256) void proj_gemm(
    const unsigned short* __restrict__ attnb,
    const unsigned short* __restrict__ Wpb, const float* __restrict__ bp,
    float* __restrict__ out)
{
  const int tid = threadIdx.x;
  const int w = tid >> 6, l = tid & 63;
  const int ln = l & 15, qu = l >> 4;
  const int sr = l >> 3, kbl = l & 7;
  const int row0 = blockIdx.x * 128;          // [c][b][n] rows
  const int col0 = blockIdx.y * 128;
  const int c = row0 >> 13;
  const int bglob = (row0 >> 10) & 7;
  const int n0 = row0 & 1023;
  const unsigned short* Ag = attnb;
  const unsigned short* W = Wpb + c * EMB * EMB;
  const float* bias = bp + c * EMB;

  __shared__ unsigned short As[2][128 * 64];
  __shared__ unsigned short Bs[2][128 * 64];

  const int xo = (w & 1) * 64, fo = (w >> 1) * 64;

  float4v acc[4][4];
#pragma unroll
  for (int i = 0; i < 4; ++i)
#pragma unroll
    for (int j = 0; j < 4; ++j) acc[i][j] = (float4v){0.f, 0.f, 0.f, 0.f};

  QKV_STAGE(0, 0);
  __syncthreads();
  int cur = 0;
  for (int k0 = 0; k0 < EMB; k0 += 64) {
    if (k0 + 64 < EMB) QKV_STAGE(cur ^ 1, k0 + 64);
#pragma unroll
    for (int ks = 0; ks < 2; ++ks) {
      short8v xf[4], wf[4];
#pragma unroll
      for (int i = 0; i < 4; ++i) {
        int rx = xo + 16 * i + ln;
        xf[i] = *(const short8v*)&As[cur][rx * 64 + (((ks * 4 + qu) ^ (rx & 7)) * 8)];
        int rw = fo + 16 * i + ln;
        wf[i] = *(const short8v*)&Bs[cur][rw * 64 + (((ks * 4 + qu) ^ (rw & 7)) * 8)];
      }
#pragma unroll
      for (int i = 0; i < 4; ++i)
#pragma unroll
        for (int j = 0; j < 4; ++j) acc[i][j] = MFMA(wf[j], xf[i], acc[i][j]);
    }
    __syncthreads();
    cur ^= 1;
  }

#pragma unroll
  for (int j = 0; j < 4; ++j) {              // f (M side)
    int f0 = col0 + fo + 16 * j + 4 * qu;    // + r
    float4 b4 = *(const float4*)&bias[f0];
#pragma unroll
    for (int i = 0; i < 4; ++i) {            // token (N side)
      int srow = bglob * SEQ + c * NCK + n0 + xo + 16 * i + ln;
      float4 o;
      o.x = acc[i][j][0] + b4.x;
      o.y = acc[i][j][1] + b4.y;
      o.z = acc[i][j][2] + b4.z;
      o.w = acc[i][j][3] + b4.w;
      *(float4*)&out[(size_t)srow * EMB + f0] = o;
    }
  }
}

extern "C" void kernel_launch(void* const* d_in, const int* in_sizes, int n_in,
                              void* d_out, int out_size, void* d_ws, size_t ws_size,
                              hipStream_t stream) {
  (void)in_sizes; (void)n_in; (void)out_size; (void)ws_size;
  const float* x  = (const float*)d_in[0];
  const float* Wq = (const float*)d_in[1];
  const float* bq = (const float*)d_in[2];
  const float* Wk = (const float*)d_in[3];
  const float* bk = (const float*)d_in[4];
  const float* Wv = (const float*)d_in[5];
  const float* bv = (const float*)d_in[6];
  const float* Wp = (const float*)d_in[7];
  const float* bp = (const float*)d_in[8];
  float* out = (float*)d_out;

  // workspace layout (bf16 elems): [Wb 4*WELEMS][qt][kt][vt][attn(=x_bf)]
  // = 6.3 MB + 4*25.2 MB = 107 MB. x_bf aliases the attn slot: x_bf is only
  // read by qkv_gemm, which completes before attn_kernel writes attnb.
  unsigned short* Wb   = (unsigned short*)d_ws;
  unsigned short* qt   = Wb + 4 * (size_t)WELEMS;
  unsigned short* kt   = qt + QKV_ELEMS;
  unsigned short* vt   = kt + QKV_ELEMS;
  unsigned short* attn = vt + QKV_ELEMS;
  unsigned short* xbf  = attn;  // alias (see above)

  conv_x<<<QKV_ELEMS / (256 * 8), 256, 0, stream>>>(x, xbf);
  conv_w<<<dim3(WELEMS / (256 * 8), 4), 256, 0, stream>>>(Wq, Wk, Wv, Wp, Wb);
  qkv_gemm<<<dim3(MTOT / 128, EMB / 128, 3), 256, 0, stream>>>(
      xbf, Wb, bq, bk, bv, qt, kt, vt);
  attn_kernel<<<(NCK / 256) * CHUNKS * BATCH * NH, 512, 0, stream>>>(qt, kt, vt, attn);
  proj_gemm<<<dim3(MTOT / 128, EMB / 128), 256, 0, stream>>>(attn, Wb + 3 * (size_t)WELEMS, bp, out);
}

// Round 9
// 267.124 us; speedup vs baseline: 1.1353x; 1.1353x over previous
//
#include <hip/hip_runtime.h>
#include <hip/hip_bf16.h>

// CSMultiHeadAttention. B=8, S=3072 (3x1024), E=512, H=8, d=64.
// fp32 I/O, bf16 workspace, fp32 MFMA accumulate.
// R5: attn 512 threads / 8 waves / 256 q rows; Q pre-scaled by SM_SCALE*log2e.
// R7/R8/R9: attn P-path in-register (permlane 4x4 transpose, VERIFIED:
//   absmax 4.9e-4), pack2r packing (cvt_pk rounding differs -> fails),
//   Ps LDS deleted, T5 setprio around attn MFMA clusters.
// R10: T3 2-phase dbuf everywhere. qkv 71.6->100.5us REGRESSION (64KB LDS ->
//   occupancy 18.4->10.8%, FETCH 80->126MB); attn (32KB, not binding)
//   inferred IMPROVED ~70.8->~58us.
// R11: revert qkv/proj to single-buffer; KEEP attn dbuf.
// R12: + T1 XCD-chunked bijective swizzle on qkv/proj grids (x-panel sharers
//   consecutive within an XCD chunk -> panel fetched once per XCD).
// R13/R14: byte-identical resubmissions — three consecutive infra failures
//   (broker timeouts / container failure); swizzle bijectivity re-audited 3x.
//   Holding the 2-deep experiment stack rather than bundling more risk.
// MFMA 16x16x32 bf16. A/B frag: [m|n = lane&15][k = (lane>>4)*8 + j].
// C/D: col = lane&15, row = (lane>>4)*4 + reg.
// GEMM LDS tiles XOR-swizzled (block kb ^ (row&7)): free 2-way banks AND
// matches global_load_lds lane-contiguous destination.

typedef __attribute__((ext_vector_type(8))) short short8v;     // 8 bf16 (4 VGPR)
typedef __attribute__((ext_vector_type(4))) float float4v;
typedef __attribute__((ext_vector_type(4))) unsigned short ushort4v;
typedef __attribute__((ext_vector_type(4))) unsigned int uint4v;

#define CHUNKS 3
#define BATCH 8
#define SEQ 3072
#define EMB 512
#define NH 8
#define HD 64
#define NCK 1024
#define MTOT (BATCH*SEQ)                      // 24576
#define QKV_ELEMS (CHUNKS*BATCH*NH*NCK*HD)    // 12582912 (== x elem count)
#define WELEMS (CHUNKS*EMB*EMB)               // 786432 per weight tensor
// 1/sqrt(512) * log2(e): softmax exp folded to exp2
#define QSCALE 0.06375872465f

__device__ __forceinline__ unsigned short f2b(float f) {
  union { float f; unsigned int i; } x; x.f = f;
  unsigned int r = x.i + 0x7FFFu + ((x.i >> 16) & 1u);  // RNE
  return (unsigned short)(r >> 16);
}
// pack two fp32 -> two bf16 (round-half-up) in 3 VALU via v_perm
__device__ __forceinline__ unsigned int pack2r(float a, float b) {
  union { float f; unsigned int u; } xa, xb; xa.f = a; xb.f = b;
  return __builtin_amdgcn_perm(xb.u + 0x8000u, xa.u + 0x8000u, 0x07060302u);
}
__device__ __forceinline__ void gld_lds16(const unsigned short* g, unsigned short* l) {
  __builtin_amdgcn_global_load_lds(
      (const __attribute__((address_space(1))) unsigned int*)g,
      (__attribute__((address_space(3))) unsigned int*)l, 16, 0, 0);
}
#define MFMA(a, b, c) __builtin_amdgcn_mfma_f32_16x16x32_bf16(a, b, c, 0, 0, 0)

// ---------------- fp32 -> bf16 conversion (streaming) ----------------
__global__ __launch_bounds__(256) void conv_x(
    const float* __restrict__ src, unsigned short* __restrict__ dst)
{
  size_t i = ((size_t)blockIdx.x * 256 + threadIdx.x) * 8;  // grid exactly covers
  float4 a = *(const float4*)&src[i];
  float4 b = *(const float4*)&src[i + 4];
  uint4v p;
  p[0] = pack2r(a.x, a.y); p[1] = pack2r(a.z, a.w);
  p[2] = pack2r(b.x, b.y); p[3] = pack2r(b.z, b.w);
  *(uint4v*)&dst[i] = p;
}

__global__ __launch_bounds__(256) void conv_w(
    const float* __restrict__ s0, const float* __restrict__ s1,
    const float* __restrict__ s2, const float* __restrict__ s3,
    unsigned short* __restrict__ dst)
{
  const int z = blockIdx.y;
  const float* s = (z == 0) ? s0 : (z == 1) ? s1 : (z == 2) ? s2 : s3;
  size_t i = ((size_t)blockIdx.x * 256 + threadIdx.x) * 8;
  float4 a = *(const float4*)&s[i];
  float4 b = *(const float4*)&s[i + 4];
  uint4v p;
  p[0] = pack2r(a.x, a.y); p[1] = pack2r(a.z, a.w);
  p[2] = pack2r(b.x, b.y); p[3] = pack2r(b.z, b.w);
  *(uint4v*)&dst[(size_t)z * WELEMS + i] = p;
}

// ---------------- QKV projection ----------------
// 128x128 tile, BK=64, 4 waves; wave w: x-rows xo=(w&1)*64, f-cols fo=(w>>1)*64.
// Single-buffered (R11: dbuf's 64KB LDS cut occupancy -> +40% time).
// 1D grid 2304, T1 XCD-chunk swizzle (R12): lin = (bid&7)*288 + bid/8;
// col0=(lin&3)*128, z=(lin>>2)%3, row0=(lin/12)*128. Blocks sharing an
// x-panel (12: 4 col x 3 z) are consecutive within an XCD chunk.
// z<=1 (Q,K): D = W·X^T -> [f][token] -> packed b64 stores along d into [n][d].
//             Q is additionally scaled by QSCALE (softmax scale * log2e).
// z==2 (V):   D = X·W^T -> [token][f] -> packed b64 stores along n into [d][n].
__global__ __launch_bounds__(256) void qkv_gemm(
    const unsigned short* __restrict__ xb, const unsigned short* __restrict__ Wb,
    const float* __restrict__ bq, const float* __restrict__ bk,
    const float* __restrict__ bv,
    unsigned short* __restrict__ qt, unsigned short* __restrict__ kt,
    unsigned short* __restrict__ vt)
{
  const int tid = threadIdx.x;
  const int w = tid >> 6, l = tid & 63;
  const int ln = l & 15, qu = l >> 4;
  const int sr = l >> 3, kbl = l & 7;
  // T1 swizzle: 2304 blocks (%8==0 -> bijective), XCD-contiguous chunks,
  // x-panel sharers (4 col-tiles x 3 z) consecutive within a chunk.
  const int bid = blockIdx.x;
  const int lin = (bid & 7) * 288 + (bid >> 3);
  const int col0 = (lin & 3) * 128;
  const int z = (lin >> 2) % 3;
  const int row0 = (lin / 12) * 128;
  const int bglob = row0 / SEQ;
  const int c = (row0 % SEQ) / NCK;
  const int n0 = row0 % NCK;
  const unsigned short* W = Wb + (size_t)z * WELEMS + c * EMB * EMB;
  const float* bias = (z == 0 ? bq : (z == 1 ? bk : bv)) + c * EMB;
  const float oscale = (z == 0) ? QSCALE : 1.0f;

  __shared__ unsigned short As[128 * 64];   // x-tile, swizzled
  __shared__ unsigned short Bs[128 * 64];   // W-tile, swizzled

  const int xo = (w & 1) * 64, fo = (w >> 1) * 64;

  float4v acc[4][4];
#pragma unroll
  for (int i = 0; i < 4; ++i)
#pragma unroll
    for (int j = 0; j < 4; ++j) acc[i][j] = (float4v){0.f, 0.f, 0.f, 0.f};

  for (int k0 = 0; k0 < EMB; k0 += 64) {
    __syncthreads();
#pragma unroll
    for (int s = 0; s < 4; ++s) {
      int rbase = w * 32 + s * 8;
      int r = rbase + sr;                    // per-lane global row
      int kb_g = kbl ^ sr;                   // swizzled k-block
      gld_lds16(&xb[(size_t)(row0 + r) * EMB + k0 + kb_g * 8], &As[rbase * 64]);
      gld_lds16(&W [(size_t)(col0 + r) * EMB + k0 + kb_g * 8], &Bs[rbase * 64]);
    }
    __syncthreads();
#pragma unroll
    for (int ks = 0; ks < 2; ++ks) {
      short8v xf[4], wf[4];
#pragma unroll
      for (int i = 0; i < 4; ++i) {
        int rx = xo + 16 * i + ln;
        xf[i] = *(const short8v*)&As[rx * 64 + (((ks * 4 + qu) ^ (rx & 7)) * 8)];
        int rw = fo + 16 * i + ln;
        wf[i] = *(const short8v*)&Bs[rw * 64 + (((ks * 4 + qu) ^ (rw & 7)) * 8)];
      }
      if (z <= 1) {
#pragma unroll
        for (int i = 0; i < 4; ++i)
#pragma unroll
          for (int j = 0; j < 4; ++j) acc[i][j] = MFMA(wf[j], xf[i], acc[i][j]);
      } else {
#pragma unroll
        for (int i = 0; i < 4; ++i)
#pragma unroll
          for (int j = 0; j < 4; ++j) acc[i][j] = MFMA(xf[i], wf[j], acc[i][j]);
      }
    }
  }

  if (z <= 1) {
    unsigned short* outp = (z == 0) ? qt : kt;
#pragma unroll
    for (int j = 0; j < 4; ++j) {            // f (M side)
      int f0 = col0 + fo + 16 * j + 4 * qu;  // + r
      float4 b4 = *(const float4*)&bias[f0];
      int hh = f0 >> 6, dd0 = f0 & 63;
      size_t base = ((size_t)((c * 8 + bglob) * 8 + hh)) << 16;
#pragma unroll
      for (int i = 0; i < 4; ++i) {          // token (N side)
        int n = n0 + xo + 16 * i + ln;
        ushort4v p;
#pragma unroll
        for (int r = 0; r < 4; ++r)
          p[r] = f2b((acc[i][j][r] + ((const float*)&b4)[r]) * oscale);
        *(ushort4v*)&outp[base + (size_t)n * 64 + dd0] = p;
      }
    }
  } else {
#pragma unroll
    for (int i = 0; i < 4; ++i) {            // token (M side)
      int nn0 = n0 + xo + 16 * i + 4 * qu;   // + r
#pragma unroll
      for (int j = 0; j < 4; ++j) {          // f (N side)
        int f = col0 + fo + 16 * j + ln;
        int hh = f >> 6, dd = f & 63;
        float bvv = bias[f];
        size_t base = ((size_t)((c * 8 + bglob) * 8 + hh)) << 16;
        ushort4v p;
#pragma unroll
        for (int r = 0; r < 4; ++r) p[r] = f2b(acc[i][j][r] + bvv);
        *(ushort4v*)&vt[base + (size_t)dd * 1024 + nn0] = p;
      }
    }
  }
}

// ---------------- Attention (flash, MFMA) ----------------
// 512 threads / 8 waves / 256 q rows per block; 4 q-blocks per head.
// Grid bid = qb*192 + head -> same-head blocks on one XCD (bid%8 const).
// K/V tiles double-buffered (T3 2-phase, KEPT from R10: attn LDS 32KB is not
// occupancy-binding, R5-bench inference ~-13us): STAGE(t+1) before
// compute(t), one __syncthreads() per tile.
// Per 64-key tile: S^T = K·Q^T (16 MFMA/wave); per 32-key half: exp2 ->
// pack2r -> permlane 4x4 transpose -> denominator(ones-MFMA) + O^T += V^T·P^T.
// Q is pre-scaled by 1/sqrt(512)*log2e in qkv -> raw v_exp_f32 here.
// setprio(1) wraps MFMA clusters (T5).
//
// P redistribution derivation: S^T C/D gives lane(ln,qu) the values
// S[q=ln][key=16*mt+4*qu+r]. PV B-frag needs lane(ln,qu) = P[q=ln][key=8*qu+j].
// Bit view: value with key bits (k4,k3,k2,k1) sits at source {mh=k4, l5=k3,
// l4=k2, p=k1}; target needs {l5=k4, l4=k3, word=(k2,k1)}. Realized by:
//   permlane32_swap(m00,m10); permlane32_swap(m01,m11);   // l5 <-> mh
//   permlane16_swap(m00,m10); permlane16_swap(m01,m11);   // l4 <-> old l5
// frag words = [m00, m01, m10, m11].  (VERIFIED on HW: absmax 4.9e-4.)
#define ATTN_STAGE(buf, kt0v) do {                                             \
  int r = w * 8;                                                               \
  gld_lds16(&Kg[(size_t)((kt0v) + r + sr) * 64 + ((kbl ^ sr) * 8)],            \
            &Ks[buf][r * 64]);                                                 \
  gld_lds16(&Vg[(size_t)(r + sr) * 1024 + (kt0v) + ((kbl ^ sr) * 8)],          \
            &Vs[buf][r * 64]);                                                 \
} while (0)

__global__ __launch_bounds__(512) void attn_kernel(
    const unsigned short* __restrict__ qt,
    const unsigned short* __restrict__ kt,
    const unsigned short* __restrict__ vt,
    unsigned short* __restrict__ attnb)
{
  const int tid = threadIdx.x;
  const int w = tid >> 6, l = tid & 63;
  const int ln = l & 15, qu = l >> 4;
  const int sr = l >> 3, kbl = l & 7;
  const int bid = blockIdx.x;
  const int hd = bid % 192;                  // (co,b,h)
  const int q0 = (bid / 192) * 256;
  const int co = hd >> 6;
  const int b  = (hd >> 3) & 7;
  const int h  = hd & 7;
  const int cq = (co + 1) % 3, ckv = (co + 2) % 3;
  const unsigned short* Qg = qt + ((size_t)((cq  * 8 + b) * 8 + h) << 16);
  const unsigned short* Kg = kt + ((size_t)((ckv * 8 + b) * 8 + h) << 16);
  const unsigned short* Vg = vt + ((size_t)((ckv * 8 + b) * 8 + h) << 16);

  __shared__ unsigned short Ks[2][64 * 64];  // [key][d] swizzled, dbuf, 16KB
  __shared__ unsigned short Vs[2][64 * 64];  // [d][key] swizzled, dbuf, 16KB

  short8v qf[2][2];
#pragma unroll
  for (int nt = 0; nt < 2; ++nt)
#pragma unroll
    for (int ks = 0; ks < 2; ++ks)
      qf[nt][ks] = *(const short8v*)&Qg[(size_t)(q0 + w * 32 + nt * 16 + ln) * 64 + ks * 32 + qu * 8];

  short8v onesf;
#pragma unroll
  for (int i = 0; i < 8; ++i) onesf[i] = (short)0x3F80;   // bf16 1.0

  float4v acc_o[4][2];
#pragma unroll
  for (int i = 0; i < 4; ++i)
#pragma unroll
    for (int j = 0; j < 2; ++j) acc_o[i][j] = (float4v){0.f, 0.f, 0.f, 0.f};
  float4v acc_l[2];
  acc_l[0] = (float4v){0.f, 0.f, 0.f, 0.f};
  acc_l[1] = (float4v){0.f, 0.f, 0.f, 0.f};

  ATTN_STAGE(0, 0);
  __syncthreads();
  int cur = 0;
  for (int kt0 = 0; kt0 < NCK; kt0 += 64) {
    if (kt0 + 64 < NCK) ATTN_STAGE(cur ^ 1, kt0 + 64);

    // S-phase: S^T[key][q]
    float4v sacc[4][2];
#pragma unroll
    for (int mt = 0; mt < 4; ++mt)
#pragma unroll
      for (int nt = 0; nt < 2; ++nt) sacc[mt][nt] = (float4v){0.f, 0.f, 0.f, 0.f};
    __builtin_amdgcn_s_setprio(1);
#pragma unroll
    for (int ks = 0; ks < 2; ++ks) {
#pragma unroll
      for (int mt = 0; mt < 4; ++mt) {
        int key = 16 * mt + ln;
        short8v kf = *(const short8v*)&Ks[cur][key * 64 + (((ks * 4 + qu) ^ (key & 7)) * 8)];
#pragma unroll
        for (int nt = 0; nt < 2; ++nt)
          sacc[mt][nt] = MFMA(kf, qf[nt][ks], sacc[mt][nt]);
      }
    }
    __builtin_amdgcn_s_setprio(0);

    // per 32-key half: exp2 -> pack2r -> permlane transpose -> denom + PV
#pragma unroll
    for (int ks2 = 0; ks2 < 2; ++ks2) {
      short8v pf[2];
#pragma unroll
      for (int nt = 0; nt < 2; ++nt) {
        float4v s0v = sacc[2 * ks2][nt];      // mh=0: keys 16*2ks2 + 4qu + r
        float4v s1v = sacc[2 * ks2 + 1][nt];  // mh=1: keys 16*(2ks2+1) + 4qu + r
        float a0 = __builtin_amdgcn_exp2f(s0v[0]);
        float a1 = __builtin_amdgcn_exp2f(s0v[1]);
        float a2 = __builtin_amdgcn_exp2f(s0v[2]);
        float a3 = __builtin_amdgcn_exp2f(s0v[3]);
        float b0 = __builtin_amdgcn_exp2f(s1v[0]);
        float b1 = __builtin_amdgcn_exp2f(s1v[1]);
        float b2 = __builtin_amdgcn_exp2f(s1v[2]);
        float b3 = __builtin_amdgcn_exp2f(s1v[3]);
        unsigned int m00 = pack2r(a0, a1);    // (mh0,p0)
        unsigned int m01 = pack2r(a2, a3);    // (mh0,p1)
        unsigned int m10 = pack2r(b0, b1);    // (mh1,p0)
        unsigned int m11 = pack2r(b2, b3);    // (mh1,p1)
        asm("v_permlane32_swap_b32 %0, %1" : "+v"(m00), "+v"(m10));
        asm("v_permlane32_swap_b32 %0, %1" : "+v"(m01), "+v"(m11));
        asm("v_permlane16_swap_b32 %0, %1" : "+v"(m00), "+v"(m10));
        asm("v_permlane16_swap_b32 %0, %1" : "+v"(m01), "+v"(m11));
        uint4v t; t[0] = m00; t[1] = m01; t[2] = m10; t[3] = m11;
        pf[nt] = __builtin_bit_cast(short8v, t);
      }
      __builtin_amdgcn_s_setprio(1);
#pragma unroll
      for (int nt = 0; nt < 2; ++nt)
        acc_l[nt] = MFMA(onesf, pf[nt], acc_l[nt]);   // row-sum of P
#pragma unroll
      for (int mt2 = 0; mt2 < 4; ++mt2) {
        int dd = 16 * mt2 + ln;
        short8v vf = *(const short8v*)&Vs[cur][dd * 64 + (((ks2 * 4 + qu) ^ (dd & 7)) * 8)];
#pragma unroll
        for (int nt = 0; nt < 2; ++nt)
          acc_o[mt2][nt] = MFMA(vf, pf[nt], acc_o[mt2][nt]);
      }
      __builtin_amdgcn_s_setprio(0);
    }

    __syncthreads();   // vmcnt(0): prefetch done; all waves done with buf[cur]
    cur ^= 1;
  }

  float inv[2];
  inv[0] = 1.0f / acc_l[0][0];
  inv[1] = 1.0f / acc_l[1][0];
  unsigned short* Og = attnb + (size_t)((co * 8 + b)) * NCK * EMB + h * HD;
#pragma unroll
  for (int mt = 0; mt < 4; ++mt) {
    int dd0 = 16 * mt + 4 * qu;
#pragma unroll
    for (int nt = 0; nt < 2; ++nt) {
      int q_glob = q0 + w * 32 + nt * 16 + ln;
      ushort4v p;
#pragma unroll
      for (int r = 0; r < 4; ++r) p[r] = f2b(acc_o[mt][nt][r] * inv[nt]);
      *(ushort4v*)&Og[(size_t)q_glob * EMB + dd0] = p;
    }
  }
}

// ---------------- Output projection ----------------
// A = attnb (bf16), B = Wp_bf (bf16): both via global_load_lds, single-buffer.
// 1D grid 768, T1 XCD-chunk swizzle (R12): lin=(bid&7)*96+bid/8;
// col0=(lin&3)*128, row0=(lin>>2)*128 -> 4 attnb-panel sharers consecutive.
// D = Wp·A^T -> [f][token]; fp32 float4 stores.
__global__ __launch_bounds__(256) void proj_gemm(
    const unsigned short* __restrict__ attnb,
    const unsigned short* __restrict__ Wpb, const float* __restrict__ bp,
    float* __restrict__ out)
{
  const int tid = threadIdx.x;
  const int w = tid >> 6, l = tid & 63;
  const int ln = l & 15, qu = l >> 4;
  const int sr = l >> 3, kbl = l & 7;
  const int bid = blockIdx.x;
  const int lin = (bid & 7) * 96 + (bid >> 3);
  const int col0 = (lin & 3) * 128;
  const int row0 = (lin >> 2) * 128;          // [c][b][n] rows
  const int c = row0 >> 13;
  const int bglob = (row0 >> 10) & 7;
  const int n0 = row0 & 1023;
  const unsigned short* W = Wpb + c * EMB * EMB;
  const float* bias = bp + c * EMB;

  __shared__ unsigned short As[128 * 64];
  __shared__ unsigned short Bs[128 * 64];

  const int xo = (w & 1) * 64, fo = (w >> 1) * 64;

  float4v acc[4][4];
#pragma unroll
  for (int i = 0; i < 4; ++i)
#pragma unroll
    for (int j = 0; j < 4; ++j) acc[i][j] = (float4v){0.f, 0.f, 0.f, 0.f};

  for (int k0 = 0; k0 < EMB; k0 += 64) {
    __syncthreads();
#pragma unroll
    for (int s = 0; s < 4; ++s) {
      int rbase = w * 32 + s * 8;
      int r = rbase + sr;
      int kb_g = kbl ^ sr;
      gld_lds16(&attnb[(size_t)(row0 + r) * EMB + k0 + kb_g * 8], &As[rbase * 64]);
      gld_lds16(&W    [(size_t)(col0 + r) * EMB + k0 + kb_g * 8], &Bs[rbase * 64]);
    }
    __syncthreads();
#pragma unroll
    for (int ks = 0; ks < 2; ++ks) {
      short8v xf[4], wf[4];
#pragma unroll
      for (int i = 0; i < 4; ++i) {
        int rx = xo + 16 * i + ln;
        xf[i] = *(const short8v*)&As[rx * 64 + (((ks * 4 + qu) ^ (rx & 7)) * 8)];
        int rw = fo + 16 * i + ln;
        wf[i] = *(const short8v*)&Bs[rw * 64 + (((ks * 4 + qu) ^ (rw & 7)) * 8)];
      }
#pragma unroll
      for (int i = 0; i < 4; ++i)
#pragma unroll
        for (int j = 0; j < 4; ++j) acc[i][j] = MFMA(wf[j], xf[i], acc[i][j]);
    }
  }

#pragma unroll
  for (int j = 0; j < 4; ++j) {              // f (M side)
    int f0 = col0 + fo + 16 * j + 4 * qu;    // + r
    float4 b4 = *(const float4*)&bias[f0];
#pragma unroll
    for (int i = 0; i < 4; ++i) {            // token (N side)
      int srow = bglob * SEQ + c * NCK + n0 + xo + 16 * i + ln;
      float4 o;
      o.x = acc[i][j][0] + b4.x;
      o.y = acc[i][j][1] + b4.y;
      o.z = acc[i][j][2] + b4.z;
      o.w = acc[i][j][3] + b4.w;
      *(float4*)&out[(size_t)srow * EMB + f0] = o;
    }
  }
}

extern "C" void kernel_launch(void* const* d_in, const int* in_sizes, int n_in,
                              void* d_out, int out_size, void* d_ws, size_t ws_size,
                              hipStream_t stream) {
  (void)in_sizes; (void)n_in; (void)out_size; (void)ws_size;
  const float* x  = (const float*)d_in[0];
  const float* Wq = (const float*)d_in[1];
  const float* bq = (const float*)d_in[2];
  const float* Wk = (const float*)d_in[3];
  const float* bk = (const float*)d_in[4];
  const float* Wv = (const float*)d_in[5];
  const float* bv = (const float*)d_in[6];
  const float* Wp = (const float*)d_in[7];
  const float* bp = (const float*)d_in[8];
  float* out = (float*)d_out;

  // workspace layout (bf16 elems): [Wb 4*WELEMS][qt][kt][vt][attn(=x_bf)]
  // = 6.3 MB + 4*25.2 MB = 107 MB. x_bf aliases the attn slot: x_bf is only
  // read by qkv_gemm, which completes before attn_kernel writes attnb.
  unsigned short* Wb   = (unsigned short*)d_ws;
  unsigned short* qt   = Wb + 4 * (size_t)WELEMS;
  unsigned short* kt   = qt + QKV_ELEMS;
  unsigned short* vt   = kt + QKV_ELEMS;
  unsigned short* attn = vt + QKV_ELEMS;
  unsigned short* xbf  = attn;  // alias (see above)

  conv_x<<<QKV_ELEMS / (256 * 8), 256, 0, stream>>>(x, xbf);
  conv_w<<<dim3(WELEMS / (256 * 8), 4), 256, 0, stream>>>(Wq, Wk, Wv, Wp, Wb);
  qkv_gemm<<<(MTOT / 128) * (EMB / 128) * 3, 256, 0, stream>>>(
      xbf, Wb, bq, bk, bv, qt, kt, vt);
  attn_kernel<<<(NCK / 256) * CHUNKS * BATCH * NH, 512, 0, stream>>>(qt, kt, vt, attn);
  proj_gemm<<<(MTOT / 128) * (EMB / 128), 256, 0, stream>>>(attn, Wb + 3 * (size_t)WELEMS, bp, out);
}

// Round 10
// 255.954 us; speedup vs baseline: 1.1848x; 1.0436x over previous
//
#include <hip/hip_runtime.h>
#include <hip/hip_bf16.h>

// CSMultiHeadAttention. B=8, S=3072 (3x1024), E=512, H=8, d=64.
// fp32 I/O, bf16 workspace, fp32 MFMA accumulate.
// R5: attn 512 threads / 8 waves / 256 q rows; Q pre-scaled by SM_SCALE*log2e.
// R7/R8/R9: attn P-path in-register (permlane 4x4 transpose, VERIFIED:
//   absmax 4.9e-4), pack2r packing (cvt_pk rounding differs -> fails),
//   Ps LDS deleted, T5 setprio around attn MFMA clusters.
// R10: dbuf everywhere. qkv REGRESSED (64KB LDS occupancy cliff).
// R11/R12 (VERIFIED R9 bench, 267.1us): qkv/proj single-buffer + T1
//   XCD-chunked swizzle -> {qkv+proj} -12.7us. attn dbuf A/B: 70.8 (R4,
//   single-buf) vs 73.5 (R9, dbuf) -> dbuf HURTS attn ~4%.
// R15 (this round):
//   - attn back to SINGLE-buffer (direct A/B evidence above);
//   - attn KVBLK 64->128: stage 128 keys per barrier pair (32->16 drains
//     per block), computed as two verified 64-key sub-passes. Ks[128][64]
//     (same row layout), Vs[2][64][64] (two existing sub-tiles). LDS 32KB,
//     still thread-limited 4 blocks/CU. Compute code unchanged.
//   - S-phase ks=0 MFMAs use literal-zero C (exact; kills sacc init movs).
// MFMA 16x16x32 bf16. A/B frag: [m|n = lane&15][k = (lane>>4)*8 + j].
// C/D: col = lane&15, row = (lane>>4)*4 + reg.
// GEMM LDS tiles XOR-swizzled (block kb ^ (row&7)): free 2-way banks AND
// matches global_load_lds lane-contiguous destination.

typedef __attribute__((ext_vector_type(8))) short short8v;     // 8 bf16 (4 VGPR)
typedef __attribute__((ext_vector_type(4))) float float4v;
typedef __attribute__((ext_vector_type(4))) unsigned short ushort4v;
typedef __attribute__((ext_vector_type(4))) unsigned int uint4v;

#define CHUNKS 3
#define BATCH 8
#define SEQ 3072
#define EMB 512
#define NH 8
#define HD 64
#define NCK 1024
#define MTOT (BATCH*SEQ)                      // 24576
#define QKV_ELEMS (CHUNKS*BATCH*NH*NCK*HD)    // 12582912 (== x elem count)
#define WELEMS (CHUNKS*EMB*EMB)               // 786432 per weight tensor
// 1/sqrt(512) * log2(e): softmax exp folded to exp2
#define QSCALE 0.06375872465f

__device__ __forceinline__ unsigned short f2b(float f) {
  union { float f; unsigned int i; } x; x.f = f;
  unsigned int r = x.i + 0x7FFFu + ((x.i >> 16) & 1u);  // RNE
  return (unsigned short)(r >> 16);
}
// pack two fp32 -> two bf16 (round-half-up) in 3 VALU via v_perm
__device__ __forceinline__ unsigned int pack2r(float a, float b) {
  union { float f; unsigned int u; } xa, xb; xa.f = a; xb.f = b;
  return __builtin_amdgcn_perm(xb.u + 0x8000u, xa.u + 0x8000u, 0x07060302u);
}
__device__ __forceinline__ void gld_lds16(const unsigned short* g, unsigned short* l) {
  __builtin_amdgcn_global_load_lds(
      (const __attribute__((address_space(1))) unsigned int*)g,
      (__attribute__((address_space(3))) unsigned int*)l, 16, 0, 0);
}
#define MFMA(a, b, c) __builtin_amdgcn_mfma_f32_16x16x32_bf16(a, b, c, 0, 0, 0)

// ---------------- fp32 -> bf16 conversion (streaming) ----------------
__global__ __launch_bounds__(256) void conv_x(
    const float* __restrict__ src, unsigned short* __restrict__ dst)
{
  size_t i = ((size_t)blockIdx.x * 256 + threadIdx.x) * 8;  // grid exactly covers
  float4 a = *(const float4*)&src[i];
  float4 b = *(const float4*)&src[i + 4];
  uint4v p;
  p[0] = pack2r(a.x, a.y); p[1] = pack2r(a.z, a.w);
  p[2] = pack2r(b.x, b.y); p[3] = pack2r(b.z, b.w);
  *(uint4v*)&dst[i] = p;
}

__global__ __launch_bounds__(256) void conv_w(
    const float* __restrict__ s0, const float* __restrict__ s1,
    const float* __restrict__ s2, const float* __restrict__ s3,
    unsigned short* __restrict__ dst)
{
  const int z = blockIdx.y;
  const float* s = (z == 0) ? s0 : (z == 1) ? s1 : (z == 2) ? s2 : s3;
  size_t i = ((size_t)blockIdx.x * 256 + threadIdx.x) * 8;
  float4 a = *(const float4*)&s[i];
  float4 b = *(const float4*)&s[i + 4];
  uint4v p;
  p[0] = pack2r(a.x, a.y); p[1] = pack2r(a.z, a.w);
  p[2] = pack2r(b.x, b.y); p[3] = pack2r(b.z, b.w);
  *(uint4v*)&dst[(size_t)z * WELEMS + i] = p;
}

// ---------------- QKV projection ----------------
// 128x128 tile, BK=64, 4 waves; wave w: x-rows xo=(w&1)*64, f-cols fo=(w>>1)*64.
// Single-buffered. 1D grid 2304, T1 XCD-chunk swizzle (VERIFIED R9):
// lin = (bid&7)*288 + bid/8; col0=(lin&3)*128, z=(lin>>2)%3, row0=(lin/12)*128.
// Blocks sharing an x-panel (4 col x 3 z) consecutive within an XCD chunk.
// z<=1 (Q,K): D = W·X^T -> [f][token] -> packed b64 stores along d into [n][d].
//             Q is additionally scaled by QSCALE (softmax scale * log2e).
// z==2 (V):   D = X·W^T -> [token][f] -> packed b64 stores along n into [d][n].
__global__ __launch_bounds__(256) void qkv_gemm(
    const unsigned short* __restrict__ xb, const unsigned short* __restrict__ Wb,
    const float* __restrict__ bq, const float* __restrict__ bk,
    const float* __restrict__ bv,
    unsigned short* __restrict__ qt, unsigned short* __restrict__ kt,
    unsigned short* __restrict__ vt)
{
  const int tid = threadIdx.x;
  const int w = tid >> 6, l = tid & 63;
  const int ln = l & 15, qu = l >> 4;
  const int sr = l >> 3, kbl = l & 7;
  const int bid = blockIdx.x;
  const int lin = (bid & 7) * 288 + (bid >> 3);
  const int col0 = (lin & 3) * 128;
  const int z = (lin >> 2) % 3;
  const int row0 = (lin / 12) * 128;
  const int bglob = row0 / SEQ;
  const int c = (row0 % SEQ) / NCK;
  const int n0 = row0 % NCK;
  const unsigned short* W = Wb + (size_t)z * WELEMS + c * EMB * EMB;
  const float* bias = (z == 0 ? bq : (z == 1 ? bk : bv)) + c * EMB;
  const float oscale = (z == 0) ? QSCALE : 1.0f;

  __shared__ unsigned short As[128 * 64];   // x-tile, swizzled
  __shared__ unsigned short Bs[128 * 64];   // W-tile, swizzled

  const int xo = (w & 1) * 64, fo = (w >> 1) * 64;

  float4v acc[4][4];
#pragma unroll
  for (int i = 0; i < 4; ++i)
#pragma unroll
    for (int j = 0; j < 4; ++j) acc[i][j] = (float4v){0.f, 0.f, 0.f, 0.f};

  for (int k0 = 0; k0 < EMB; k0 += 64) {
    __syncthreads();
#pragma unroll
    for (int s = 0; s < 4; ++s) {
      int rbase = w * 32 + s * 8;
      int r = rbase + sr;                    // per-lane global row
      int kb_g = kbl ^ sr;                   // swizzled k-block
      gld_lds16(&xb[(size_t)(row0 + r) * EMB + k0 + kb_g * 8], &As[rbase * 64]);
      gld_lds16(&W [(size_t)(col0 + r) * EMB + k0 + kb_g * 8], &Bs[rbase * 64]);
    }
    __syncthreads();
#pragma unroll
    for (int ks = 0; ks < 2; ++ks) {
      short8v xf[4], wf[4];
#pragma unroll
      for (int i = 0; i < 4; ++i) {
        int rx = xo + 16 * i + ln;
        xf[i] = *(const short8v*)&As[rx * 64 + (((ks * 4 + qu) ^ (rx & 7)) * 8)];
        int rw = fo + 16 * i + ln;
        wf[i] = *(const short8v*)&Bs[rw * 64 + (((ks * 4 + qu) ^ (rw & 7)) * 8)];
      }
      if (z <= 1) {
#pragma unroll
        for (int i = 0; i < 4; ++i)
#pragma unroll
          for (int j = 0; j < 4; ++j) acc[i][j] = MFMA(wf[j], xf[i], acc[i][j]);
      } else {
#pragma unroll
        for (int i = 0; i < 4; ++i)
#pragma unroll
          for (int j = 0; j < 4; ++j) acc[i][j] = MFMA(xf[i], wf[j], acc[i][j]);
      }
    }
  }

  if (z <= 1) {
    unsigned short* outp = (z == 0) ? qt : kt;
#pragma unroll
    for (int j = 0; j < 4; ++j) {            // f (M side)
      int f0 = col0 + fo + 16 * j + 4 * qu;  // + r
      float4 b4 = *(const float4*)&bias[f0];
      int hh = f0 >> 6, dd0 = f0 & 63;
      size_t base = ((size_t)((c * 8 + bglob) * 8 + hh)) << 16;
#pragma unroll
      for (int i = 0; i < 4; ++i) {          // token (N side)
        int n = n0 + xo + 16 * i + ln;
        ushort4v p;
#pragma unroll
        for (int r = 0; r < 4; ++r)
          p[r] = f2b((acc[i][j][r] + ((const float*)&b4)[r]) * oscale);
        *(ushort4v*)&outp[base + (size_t)n * 64 + dd0] = p;
      }
    }
  } else {
#pragma unroll
    for (int i = 0; i < 4; ++i) {            // token (M side)
      int nn0 = n0 + xo + 16 * i + 4 * qu;   // + r
#pragma unroll
      for (int j = 0; j < 4; ++j) {          // f (N side)
        int f = col0 + fo + 16 * j + ln;
        int hh = f >> 6, dd = f & 63;
        float bvv = bias[f];
        size_t base = ((size_t)((c * 8 + bglob) * 8 + hh)) << 16;
        ushort4v p;
#pragma unroll
        for (int r = 0; r < 4; ++r) p[r] = f2b(acc[i][j][r] + bvv);
        *(ushort4v*)&vt[base + (size_t)dd * 1024 + nn0] = p;
      }
    }
  }
}

// ---------------- Attention (flash, MFMA) ----------------
// 512 threads / 8 waves / 256 q rows per block; 4 q-blocks per head.
// Grid bid = qb*192 + head -> same-head blocks on one XCD (bid%8 = head%8).
// R15: SINGLE-buffered (dbuf A/B: 70.8 vs 73.5 -> dbuf hurts), KVBLK=128:
// one barrier pair stages 128 keys (Ks[128][64], Vs[2][64][64], 32KB),
// then TWO verified 64-key sub-passes. 16 barrier+drain per block (was 32).
// Per 64-key sub-pass: S^T = K·Q^T (16 MFMA/wave, ks=0 uses literal-zero C);
// per 32-key half: exp2 -> pack2r -> permlane 4x4 transpose ->
// denominator(ones-MFMA) + O^T += V^T·P^T.
// Q is pre-scaled by 1/sqrt(512)*log2e in qkv -> raw v_exp_f32 here.
// setprio(1) wraps MFMA clusters (T5).
//
// P redistribution derivation: S^T C/D gives lane(ln,qu) the values
// S[q=ln][key=16*mt+4*qu+r]. PV B-frag needs lane(ln,qu) = P[q=ln][key=8*qu+j].
// Bit view: value with key bits (k4,k3,k2,k1) sits at source {mh=k4, l5=k3,
// l4=k2, p=k1}; target needs {l5=k4, l4=k3, word=(k2,k1)}. Realized by:
//   permlane32_swap(m00,m10); permlane32_swap(m01,m11);   // l5 <-> mh
//   permlane16_swap(m00,m10); permlane16_swap(m01,m11);   // l4 <-> old l5
// frag words = [m00, m01, m10, m11].  (VERIFIED on HW: absmax 4.9e-4.)
__global__ __launch_bounds__(512) void attn_kernel(
    const unsigned short* __restrict__ qt,
    const unsigned short* __restrict__ kt,
    const unsigned short* __restrict__ vt,
    unsigned short* __restrict__ attnb)
{
  const int tid = threadIdx.x;
  const int w = tid >> 6, l = tid & 63;
  const int ln = l & 15, qu = l >> 4;
  const int sr = l >> 3, kbl = l & 7;
  const int bid = blockIdx.x;
  const int hd = bid % 192;                  // (co,b,h)
  const int q0 = (bid / 192) * 256;
  const int co = hd >> 6;
  const int b  = (hd >> 3) & 7;
  const int h  = hd & 7;
  const int cq = (co + 1) % 3, ckv = (co + 2) % 3;
  const unsigned short* Qg = qt + ((size_t)((cq  * 8 + b) * 8 + h) << 16);
  const unsigned short* Kg = kt + ((size_t)((ckv * 8 + b) * 8 + h) << 16);
  const unsigned short* Vg = vt + ((size_t)((ckv * 8 + b) * 8 + h) << 16);

  __shared__ unsigned short Ks[128 * 64];    // [key][d] swizzled, 16KB
  __shared__ unsigned short Vs[2][64 * 64];  // two [d][key] sub-tiles, 16KB

  short8v qf[2][2];
#pragma unroll
  for (int nt = 0; nt < 2; ++nt)
#pragma unroll
    for (int ks = 0; ks < 2; ++ks)
      qf[nt][ks] = *(const short8v*)&Qg[(size_t)(q0 + w * 32 + nt * 16 + ln) * 64 + ks * 32 + qu * 8];

  short8v onesf;
#pragma unroll
  for (int i = 0; i < 8; ++i) onesf[i] = (short)0x3F80;   // bf16 1.0
  const float4v zf = (float4v){0.f, 0.f, 0.f, 0.f};

  float4v acc_o[4][2];
#pragma unroll
  for (int i = 0; i < 4; ++i)
#pragma unroll
    for (int j = 0; j < 2; ++j) acc_o[i][j] = (float4v){0.f, 0.f, 0.f, 0.f};
  float4v acc_l[2];
  acc_l[0] = zf;
  acc_l[1] = zf;

  for (int kt0 = 0; kt0 < NCK; kt0 += 128) {
    __syncthreads();                         // all waves done with prev tile
    {
      int rK = w * 16;                       // 16 K-rows per wave (2 issues)
      gld_lds16(&Kg[(size_t)(kt0 + rK + sr) * 64 + ((kbl ^ sr) * 8)],
                &Ks[rK * 64]);
      gld_lds16(&Kg[(size_t)(kt0 + rK + 8 + sr) * 64 + ((kbl ^ sr) * 8)],
                &Ks[(rK + 8) * 64]);
      int rV = w * 8;                        // 8 d-rows per wave per sub-tile
      gld_lds16(&Vg[(size_t)(rV + sr) * 1024 + kt0 + ((kbl ^ sr) * 8)],
                &Vs[0][rV * 64]);
      gld_lds16(&Vg[(size_t)(rV + sr) * 1024 + kt0 + 64 + ((kbl ^ sr) * 8)],
                &Vs[1][rV * 64]);
    }
    __syncthreads();                         // vmcnt(0): tile staged

#pragma unroll
    for (int sub = 0; sub < 2; ++sub) {
      const int sub64 = sub * 64;

      // S-phase: S^T[key][q]; ks=0 writes via literal-zero C (exact)
      float4v sacc[4][2];
      __builtin_amdgcn_s_setprio(1);
#pragma unroll
      for (int mt = 0; mt < 4; ++mt) {
        int key = sub64 + 16 * mt + ln;
        short8v kf = *(const short8v*)&Ks[key * 64 + ((qu ^ (key & 7)) * 8)];
        sacc[mt][0] = MFMA(kf, qf[0][0], zf);
        sacc[mt][1] = MFMA(kf, qf[1][0], zf);
      }
#pragma unroll
      for (int mt = 0; mt < 4; ++mt) {
        int key = sub64 + 16 * mt + ln;
        short8v kf = *(const short8v*)&Ks[key * 64 + (((4 + qu) ^ (key & 7)) * 8)];
        sacc[mt][0] = MFMA(kf, qf[0][1], sacc[mt][0]);
        sacc[mt][1] = MFMA(kf, qf[1][1], sacc[mt][1]);
      }
      __builtin_amdgcn_s_setprio(0);

      // per 32-key half: exp2 -> pack2r -> permlane transpose -> denom + PV
#pragma unroll
      for (int ks2 = 0; ks2 < 2; ++ks2) {
        short8v pf[2];
#pragma unroll
        for (int nt = 0; nt < 2; ++nt) {
          float4v s0v = sacc[2 * ks2][nt];      // mh=0: keys 16*2ks2 + 4qu + r
          float4v s1v = sacc[2 * ks2 + 1][nt];  // mh=1: keys 16*(2ks2+1)+4qu+r
          float a0 = __builtin_amdgcn_exp2f(s0v[0]);
          float a1 = __builtin_amdgcn_exp2f(s0v[1]);
          float a2 = __builtin_amdgcn_exp2f(s0v[2]);
          float a3 = __builtin_amdgcn_exp2f(s0v[3]);
          float b0 = __builtin_amdgcn_exp2f(s1v[0]);
          float b1 = __builtin_amdgcn_exp2f(s1v[1]);
          float b2 = __builtin_amdgcn_exp2f(s1v[2]);
          float b3 = __builtin_amdgcn_exp2f(s1v[3]);
          unsigned int m00 = pack2r(a0, a1);    // (mh0,p0)
          unsigned int m01 = pack2r(a2, a3);    // (mh0,p1)
          unsigned int m10 = pack2r(b0, b1);    // (mh1,p0)
          unsigned int m11 = pack2r(b2, b3);    // (mh1,p1)
          asm("v_permlane32_swap_b32 %0, %1" : "+v"(m00), "+v"(m10));
          asm("v_permlane32_swap_b32 %0, %1" : "+v"(m01), "+v"(m11));
          asm("v_permlane16_swap_b32 %0, %1" : "+v"(m00), "+v"(m10));
          asm("v_permlane16_swap_b32 %0, %1" : "+v"(m01), "+v"(m11));
          uint4v t; t[0] = m00; t[1] = m01; t[2] = m10; t[3] = m11;
          pf[nt] = __builtin_bit_cast(short8v, t);
        }
        __builtin_amdgcn_s_setprio(1);
#pragma unroll
        for (int nt = 0; nt < 2; ++nt)
          acc_l[nt] = MFMA(onesf, pf[nt], acc_l[nt]);   // row-sum of P
#pragma unroll
        for (int mt2 = 0; mt2 < 4; ++mt2) {
          int dd = 16 * mt2 + ln;
          short8v vf = *(const short8v*)&Vs[sub][dd * 64 + (((ks2 * 4 + qu) ^ (dd & 7)) * 8)];
#pragma unroll
          for (int nt = 0; nt < 2; ++nt)
            acc_o[mt2][nt] = MFMA(vf, pf[nt], acc_o[mt2][nt]);
        }
        __builtin_amdgcn_s_setprio(0);
      }
    }
  }

  float inv[2];
  inv[0] = 1.0f / acc_l[0][0];
  inv[1] = 1.0f / acc_l[1][0];
  unsigned short* Og = attnb + (size_t)((co * 8 + b)) * NCK * EMB + h * HD;
#pragma unroll
  for (int mt = 0; mt < 4; ++mt) {
    int dd0 = 16 * mt + 4 * qu;
#pragma unroll
    for (int nt = 0; nt < 2; ++nt) {
      int q_glob = q0 + w * 32 + nt * 16 + ln;
      ushort4v p;
#pragma unroll
      for (int r = 0; r < 4; ++r) p[r] = f2b(acc_o[mt][nt][r] * inv[nt]);
      *(ushort4v*)&Og[(size_t)q_glob * EMB + dd0] = p;
    }
  }
}

// ---------------- Output projection ----------------
// A = attnb (bf16), B = Wp_bf (bf16): both via global_load_lds, single-buffer.
// 1D grid 768, T1 XCD-chunk swizzle (VERIFIED R9): lin=(bid&7)*96+bid/8;
// col0=(lin&3)*128, row0=(lin>>2)*128 -> 4 attnb-panel sharers consecutive.
// D = Wp·A^T -> [f][token]; fp32 float4 stores.
__global__ __launch_bounds__(256) void proj_gemm(
    const unsigned short* __restrict__ attnb,
    const unsigned short* __restrict__ Wpb, const float* __restrict__ bp,
    float* __restrict__ out)
{
  const int tid = threadIdx.x;
  const int w = tid >> 6, l = tid & 63;
  const int ln = l & 15, qu = l >> 4;
  const int sr = l >> 3, kbl = l & 7;
  const int bid = blockIdx.x;
  const int lin = (bid & 7) * 96 + (bid >> 3);
  const int col0 = (lin & 3) * 128;
  const int row0 = (lin >> 2) * 128;          // [c][b][n] rows
  const int c = row0 >> 13;
  const int bglob = (row0 >> 10) & 7;
  const int n0 = row0 & 1023;
  const unsigned short* W = Wpb + c * EMB * EMB;
  const float* bias = bp + c * EMB;

  __shared__ unsigned short As[128 * 64];
  __shared__ unsigned short Bs[128 * 64];

  const int xo = (w & 1) * 64, fo = (w >> 1) * 64;

  float4v acc[4][4];
#pragma unroll
  for (int i = 0; i < 4; ++i)
#pragma unroll
    for (int j = 0; j < 4; ++j) acc[i][j] = (float4v){0.f, 0.f, 0.f, 0.f};

  for (int k0 = 0; k0 < EMB; k0 += 64) {
    __syncthreads();
#pragma unroll
    for (int s = 0; s < 4; ++s) {
      int rbase = w * 32 + s * 8;
      int r = rbase + sr;
      int kb_g = kbl ^ sr;
      gld_lds16(&attnb[(size_t)(row0 + r) * EMB + k0 + kb_g * 8], &As[rbase * 64]);
      gld_lds16(&W    [(size_t)(col0 + r) * EMB + k0 + kb_g * 8], &Bs[rbase * 64]);
    }
    __syncthreads();
#pragma unroll
    for (int ks = 0; ks < 2; ++ks) {
      short8v xf[4], wf[4];
#pragma unroll
      for (int i = 0; i < 4; ++i) {
        int rx = xo + 16 * i + ln;
        xf[i] = *(const short8v*)&As[rx * 64 + (((ks * 4 + qu) ^ (rx & 7)) * 8)];
        int rw = fo + 16 * i + ln;
        wf[i] = *(const short8v*)&Bs[rw * 64 + (((ks * 4 + qu) ^ (rw & 7)) * 8)];
      }
#pragma unroll
      for (int i = 0; i < 4; ++i)
#pragma unroll
        for (int j = 0; j < 4; ++j) acc[i][j] = MFMA(wf[j], xf[i], acc[i][j]);
    }
  }

#pragma unroll
  for (int j = 0; j < 4; ++j) {              // f (M side)
    int f0 = col0 + fo + 16 * j + 4 * qu;    // + r
    float4 b4 = *(const float4*)&bias[f0];
#pragma unroll
    for (int i = 0; i < 4; ++i) {            // token (N side)
      int srow = bglob * SEQ + c * NCK + n0 + xo + 16 * i + ln;
      float4 o;
      o.x = acc[i][j][0] + b4.x;
      o.y = acc[i][j][1] + b4.y;
      o.z = acc[i][j][2] + b4.z;
      o.w = acc[i][j][3] + b4.w;
      *(float4*)&out[(size_t)srow * EMB + f0] = o;
    }
  }
}

extern "C" void kernel_launch(void* const* d_in, const int* in_sizes, int n_in,
                              void* d_out, int out_size, void* d_ws, size_t ws_size,
                              hipStream_t stream) {
  (void)in_sizes; (void)n_in; (void)out_size; (void)ws_size;
  const float* x  = (const float*)d_in[0];
  const float* Wq = (const float*)d_in[1];
  const float* bq = (const float*)d_in[2];
  const float* Wk = (const float*)d_in[3];
  const float* bk = (const float*)d_in[4];
  const float* Wv = (const float*)d_in[5];
  const float* bv = (const float*)d_in[6];
  const float* Wp = (const float*)d_in[7];
  const float* bp = (const float*)d_in[8];
  float* out = (float*)d_out;

  // workspace layout (bf16 elems): [Wb 4*WELEMS][qt][kt][vt][attn(=x_bf)]
  // = 6.3 MB + 4*25.2 MB = 107 MB. x_bf aliases the attn slot: x_bf is only
  // read by qkv_gemm, which completes before attn_kernel writes attnb.
  unsigned short* Wb   = (unsigned short*)d_ws;
  unsigned short* qt   = Wb + 4 * (size_t)WELEMS;
  unsigned short* kt   = qt + QKV_ELEMS;
  unsigned short* vt   = kt + QKV_ELEMS;
  unsigned short* attn = vt + QKV_ELEMS;
  unsigned short* xbf  = attn;  // alias (see above)

  conv_x<<<QKV_ELEMS / (256 * 8), 256, 0, stream>>>(x, xbf);
  conv_w<<<dim3(WELEMS / (256 * 8), 4), 256, 0, stream>>>(Wq, Wk, Wv, Wp, Wb);
  qkv_gemm<<<(MTOT / 128) * (EMB / 128) * 3, 256, 0, stream>>>(
      xbf, Wb, bq, bk, bv, qt, kt, vt);
  attn_kernel<<<(NCK / 256) * CHUNKS * BATCH * NH, 512, 0, stream>>>(qt, kt, vt, attn);
  proj_gemm<<<(MTOT / 128) * (EMB / 128), 256, 0, stream>>>(attn, Wb + 3 * (size_t)WELEMS, bp, out);
}

// Round 12
// 252.202 us; speedup vs baseline: 1.2024x; 1.0149x over previous
//
#include <hip/hip_runtime.h>
#include <hip/hip_bf16.h>

// CSMultiHeadAttention. B=8, S=3072 (3x1024), E=512, H=8, d=64.
// fp32 I/O, bf16 workspace, fp32 MFMA accumulate.
// R5: attn 512 threads / 8 waves / 256 q rows; Q pre-scaled by SM_SCALE*log2e.
// R7/R8/R9: attn P-path in-register (permlane 4x4 transpose, VERIFIED:
//   absmax 4.9e-4), pack2r packing (cvt_pk rounding differs -> fails),
//   Ps LDS deleted, T5 setprio around attn MFMA clusters.
// R10: dbuf everywhere -> qkv REGRESSED (64KB LDS occupancy cliff).
// R11/R12 (VERIFIED, 267.1us): qkv/proj single-buffer + T1 XCD swizzle.
// R15 (VERIFIED, 256.0us): attn single-buffer + KVBLK=128 (16 drains/block)
//   + literal-zero C in S-phase. attn 73.5->69.4us. FETCH 73.9MB = KV+Q
//   read exactly once (no re-fetch).
// R16/R17: conv_x + conv_w merged into ONE conv_all launch (calibration
//   probe for per-kernel-boundary cost: per-dispatch sums ~180us vs wall
//   256us). R17 = byte-identical resubmission after infra timeout; probe
//   held unbundled so the wall-clock delta cleanly measures one boundary.
// MFMA 16x16x32 bf16. A/B frag: [m|n = lane&15][k = (lane>>4)*8 + j].
// C/D: col = lane&15, row = (lane>>4)*4 + reg.
// GEMM LDS tiles XOR-swizzled (block kb ^ (row&7)): free 2-way banks AND
// matches global_load_lds lane-contiguous destination.

typedef __attribute__((ext_vector_type(8))) short short8v;     // 8 bf16 (4 VGPR)
typedef __attribute__((ext_vector_type(4))) float float4v;
typedef __attribute__((ext_vector_type(4))) unsigned short ushort4v;
typedef __attribute__((ext_vector_type(4))) unsigned int uint4v;

#define CHUNKS 3
#define BATCH 8
#define SEQ 3072
#define EMB 512
#define NH 8
#define HD 64
#define NCK 1024
#define MTOT (BATCH*SEQ)                      // 24576
#define QKV_ELEMS (CHUNKS*BATCH*NH*NCK*HD)    // 12582912 (== x elem count)
#define WELEMS (CHUNKS*EMB*EMB)               // 786432 per weight tensor
#define XCONV_BLOCKS (QKV_ELEMS / (256 * 8))  // 6144
#define WCONV_BLOCKS (WELEMS / (256 * 8))     // 384 per weight tensor
// 1/sqrt(512) * log2(e): softmax exp folded to exp2
#define QSCALE 0.06375872465f

__device__ __forceinline__ unsigned short f2b(float f) {
  union { float f; unsigned int i; } x; x.f = f;
  unsigned int r = x.i + 0x7FFFu + ((x.i >> 16) & 1u);  // RNE
  return (unsigned short)(r >> 16);
}
// pack two fp32 -> two bf16 (round-half-up) in 3 VALU via v_perm
__device__ __forceinline__ unsigned int pack2r(float a, float b) {
  union { float f; unsigned int u; } xa, xb; xa.f = a; xb.f = b;
  return __builtin_amdgcn_perm(xb.u + 0x8000u, xa.u + 0x8000u, 0x07060302u);
}
__device__ __forceinline__ void gld_lds16(const unsigned short* g, unsigned short* l) {
  __builtin_amdgcn_global_load_lds(
      (const __attribute__((address_space(1))) unsigned int*)g,
      (__attribute__((address_space(3))) unsigned int*)l, 16, 0, 0);
}
#define MFMA(a, b, c) __builtin_amdgcn_mfma_f32_16x16x32_bf16(a, b, c, 0, 0, 0)

// ---------------- fp32 -> bf16 conversion (streaming, single launch) -------
// Blocks [0, XCONV_BLOCKS): convert x -> xbf.
// Blocks [XCONV_BLOCKS, +4*WCONV_BLOCKS): convert Wq/Wk/Wv/Wp -> Wb.
__global__ __launch_bounds__(256) void conv_all(
    const float* __restrict__ x,
    const float* __restrict__ s0, const float* __restrict__ s1,
    const float* __restrict__ s2, const float* __restrict__ s3,
    unsigned short* __restrict__ xbf, unsigned short* __restrict__ Wb)
{
  const int bid = blockIdx.x;
  const float* src;
  unsigned short* dst;
  size_t i;
  if (bid < XCONV_BLOCKS) {
    i = ((size_t)bid * 256 + threadIdx.x) * 8;
    src = x;
    dst = xbf;
  } else {
    const int wb = bid - XCONV_BLOCKS;
    const int z = wb / WCONV_BLOCKS;
    i = ((size_t)(wb % WCONV_BLOCKS) * 256 + threadIdx.x) * 8;
    src = (z == 0) ? s0 : (z == 1) ? s1 : (z == 2) ? s2 : s3;
    dst = Wb + (size_t)z * WELEMS;
  }
  float4 a = *(const float4*)&src[i];
  float4 b = *(const float4*)&src[i + 4];
  uint4v p;
  p[0] = pack2r(a.x, a.y); p[1] = pack2r(a.z, a.w);
  p[2] = pack2r(b.x, b.y); p[3] = pack2r(b.z, b.w);
  *(uint4v*)&dst[i] = p;
}

// ---------------- QKV projection ----------------
// 128x128 tile, BK=64, 4 waves; wave w: x-rows xo=(w&1)*64, f-cols fo=(w>>1)*64.
// Single-buffered. 1D grid 2304, T1 XCD-chunk swizzle (VERIFIED R9):
// lin = (bid&7)*288 + bid/8; col0=(lin&3)*128, z=(lin>>2)%3, row0=(lin/12)*128.
// Blocks sharing an x-panel (4 col x 3 z) consecutive within an XCD chunk.
// z<=1 (Q,K): D = W·X^T -> [f][token] -> packed b64 stores along d into [n][d].
//             Q is additionally scaled by QSCALE (softmax scale * log2e).
// z==2 (V):   D = X·W^T -> [token][f] -> packed b64 stores along n into [d][n].
__global__ __launch_bounds__(256) void qkv_gemm(
    const unsigned short* __restrict__ xb, const unsigned short* __restrict__ Wb,
    const float* __restrict__ bq, const float* __restrict__ bk,
    const float* __restrict__ bv,
    unsigned short* __restrict__ qt, unsigned short* __restrict__ kt,
    unsigned short* __restrict__ vt)
{
  const int tid = threadIdx.x;
  const int w = tid >> 6, l = tid & 63;
  const int ln = l & 15, qu = l >> 4;
  const int sr = l >> 3, kbl = l & 7;
  const int bid = blockIdx.x;
  const int lin = (bid & 7) * 288 + (bid >> 3);
  const int col0 = (lin & 3) * 128;
  const int z = (lin >> 2) % 3;
  const int row0 = (lin / 12) * 128;
  const int bglob = row0 / SEQ;
  const int c = (row0 % SEQ) / NCK;
  const int n0 = row0 % NCK;
  const unsigned short* W = Wb + (size_t)z * WELEMS + c * EMB * EMB;
  const float* bias = (z == 0 ? bq : (z == 1 ? bk : bv)) + c * EMB;
  const float oscale = (z == 0) ? QSCALE : 1.0f;

  __shared__ unsigned short As[128 * 64];   // x-tile, swizzled
  __shared__ unsigned short Bs[128 * 64];   // W-tile, swizzled

  const int xo = (w & 1) * 64, fo = (w >> 1) * 64;

  float4v acc[4][4];
#pragma unroll
  for (int i = 0; i < 4; ++i)
#pragma unroll
    for (int j = 0; j < 4; ++j) acc[i][j] = (float4v){0.f, 0.f, 0.f, 0.f};

  for (int k0 = 0; k0 < EMB; k0 += 64) {
    __syncthreads();
#pragma unroll
    for (int s = 0; s < 4; ++s) {
      int rbase = w * 32 + s * 8;
      int r = rbase + sr;                    // per-lane global row
      int kb_g = kbl ^ sr;                   // swizzled k-block
      gld_lds16(&xb[(size_t)(row0 + r) * EMB + k0 + kb_g * 8], &As[rbase * 64]);
      gld_lds16(&W [(size_t)(col0 + r) * EMB + k0 + kb_g * 8], &Bs[rbase * 64]);
    }
    __syncthreads();
#pragma unroll
    for (int ks = 0; ks < 2; ++ks) {
      short8v xf[4], wf[4];
#pragma unroll
      for (int i = 0; i < 4; ++i) {
        int rx = xo + 16 * i + ln;
        xf[i] = *(const short8v*)&As[rx * 64 + (((ks * 4 + qu) ^ (rx & 7)) * 8)];
        int rw = fo + 16 * i + ln;
        wf[i] = *(const short8v*)&Bs[rw * 64 + (((ks * 4 + qu) ^ (rw & 7)) * 8)];
      }
      if (z <= 1) {
#pragma unroll
        for (int i = 0; i < 4; ++i)
#pragma unroll
          for (int j = 0; j < 4; ++j) acc[i][j] = MFMA(wf[j], xf[i], acc[i][j]);
      } else {
#pragma unroll
        for (int i = 0; i < 4; ++i)
#pragma unroll
          for (int j = 0; j < 4; ++j) acc[i][j] = MFMA(xf[i], wf[j], acc[i][j]);
      }
    }
  }

  if (z <= 1) {
    unsigned short* outp = (z == 0) ? qt : kt;
#pragma unroll
    for (int j = 0; j < 4; ++j) {            // f (M side)
      int f0 = col0 + fo + 16 * j + 4 * qu;  // + r
      float4 b4 = *(const float4*)&bias[f0];
      int hh = f0 >> 6, dd0 = f0 & 63;
      size_t base = ((size_t)((c * 8 + bglob) * 8 + hh)) << 16;
#pragma unroll
      for (int i = 0; i < 4; ++i) {          // token (N side)
        int n = n0 + xo + 16 * i + ln;
        ushort4v p;
#pragma unroll
        for (int r = 0; r < 4; ++r)
          p[r] = f2b((acc[i][j][r] + ((const float*)&b4)[r]) * oscale);
        *(ushort4v*)&outp[base + (size_t)n * 64 + dd0] = p;
      }
    }
  } else {
#pragma unroll
    for (int i = 0; i < 4; ++i) {            // token (M side)
      int nn0 = n0 + xo + 16 * i + 4 * qu;   // + r
#pragma unroll
      for (int j = 0; j < 4; ++j) {          // f (N side)
        int f = col0 + fo + 16 * j + ln;
        int hh = f >> 6, dd = f & 63;
        float bvv = bias[f];
        size_t base = ((size_t)((c * 8 + bglob) * 8 + hh)) << 16;
        ushort4v p;
#pragma unroll
        for (int r = 0; r < 4; ++r) p[r] = f2b(acc[i][j][r] + bvv);
        *(ushort4v*)&vt[base + (size_t)dd * 1024 + nn0] = p;
      }
    }
  }
}

// ---------------- Attention (flash, MFMA) ----------------
// 512 threads / 8 waves / 256 q rows per block; 4 q-blocks per head.
// Grid bid = qb*192 + head -> same-head blocks on one XCD (bid%8 = head%8).
// SINGLE-buffered (dbuf A/B: 70.8 vs 73.5 -> dbuf hurts), KVBLK=128:
// one barrier pair stages 128 keys (Ks[128][64], Vs[2][64][64], 32KB),
// then TWO verified 64-key sub-passes. 16 barrier+drain per block.
// Per 64-key sub-pass: S^T = K·Q^T (16 MFMA/wave, ks=0 uses literal-zero C);
// per 32-key half: exp2 -> pack2r -> permlane 4x4 transpose ->
// denominator(ones-MFMA) + O^T += V^T·P^T.
// Q is pre-scaled by 1/sqrt(512)*log2e in qkv -> raw v_exp_f32 here.
// setprio(1) wraps MFMA clusters (T5).
//
// P redistribution derivation: S^T C/D gives lane(ln,qu) the values
// S[q=ln][key=16*mt+4*qu+r]. PV B-frag needs lane(ln,qu) = P[q=ln][key=8*qu+j].
// Bit view: value with key bits (k4,k3,k2,k1) sits at source {mh=k4, l5=k3,
// l4=k2, p=k1}; target needs {l5=k4, l4=k3, word=(k2,k1)}. Realized by:
//   permlane32_swap(m00,m10); permlane32_swap(m01,m11);   // l5 <-> mh
//   permlane16_swap(m00,m10); permlane16_swap(m01,m11);   // l4 <-> old l5
// frag words = [m00, m01, m10, m11].  (VERIFIED on HW: absmax 4.9e-4.)
__global__ __launch_bounds__(512) void attn_kernel(
    const unsigned short* __restrict__ qt,
    const unsigned short* __restrict__ kt,
    const unsigned short* __restrict__ vt,
    unsigned short* __restrict__ attnb)
{
  const int tid = threadIdx.x;
  const int w = tid >> 6, l = tid & 63;
  const int ln = l & 15, qu = l >> 4;
  const int sr = l >> 3, kbl = l & 7;
  const int bid = blockIdx.x;
  const int hd = bid % 192;                  // (co,b,h)
  const int q0 = (bid / 192) * 256;
  const int co = hd >> 6;
  const int b  = (hd >> 3) & 7;
  const int h  = hd & 7;
  const int cq = (co + 1) % 3, ckv = (co + 2) % 3;
  const unsigned short* Qg = qt + ((size_t)((cq  * 8 + b) * 8 + h) << 16);
  const unsigned short* Kg = kt + ((size_t)((ckv * 8 + b) * 8 + h) << 16);
  const unsigned short* Vg = vt + ((size_t)((ckv * 8 + b) * 8 + h) << 16);

  __shared__ unsigned short Ks[128 * 64];    // [key][d] swizzled, 16KB
  __shared__ unsigned short Vs[2][64 * 64];  // two [d][key] sub-tiles, 16KB

  short8v qf[2][2];
#pragma unroll
  for (int nt = 0; nt < 2; ++nt)
#pragma unroll
    for (int ks = 0; ks < 2; ++ks)
      qf[nt][ks] = *(const short8v*)&Qg[(size_t)(q0 + w * 32 + nt * 16 + ln) * 64 + ks * 32 + qu * 8];

  short8v onesf;
#pragma unroll
  for (int i = 0; i < 8; ++i) onesf[i] = (short)0x3F80;   // bf16 1.0
  const float4v zf = (float4v){0.f, 0.f, 0.f, 0.f};

  float4v acc_o[4][2];
#pragma unroll
  for (int i = 0; i < 4; ++i)
#pragma unroll
    for (int j = 0; j < 2; ++j) acc_o[i][j] = (float4v){0.f, 0.f, 0.f, 0.f};
  float4v acc_l[2];
  acc_l[0] = zf;
  acc_l[1] = zf;

  for (int kt0 = 0; kt0 < NCK; kt0 += 128) {
    __syncthreads();                         // all waves done with prev tile
    {
      int rK = w * 16;                       // 16 K-rows per wave (2 issues)
      gld_lds16(&Kg[(size_t)(kt0 + rK + sr) * 64 + ((kbl ^ sr) * 8)],
                &Ks[rK * 64]);
      gld_lds16(&Kg[(size_t)(kt0 + rK + 8 + sr) * 64 + ((kbl ^ sr) * 8)],
                &Ks[(rK + 8) * 64]);
      int rV = w * 8;                        // 8 d-rows per wave per sub-tile
      gld_lds16(&Vg[(size_t)(rV + sr) * 1024 + kt0 + ((kbl ^ sr) * 8)],
                &Vs[0][rV * 64]);
      gld_lds16(&Vg[(size_t)(rV + sr) * 1024 + kt0 + 64 + ((kbl ^ sr) * 8)],
                &Vs[1][rV * 64]);
    }
    __syncthreads();                         // vmcnt(0): tile staged

#pragma unroll
    for (int sub = 0; sub < 2; ++sub) {
      const int sub64 = sub * 64;

      // S-phase: S^T[key][q]; ks=0 writes via literal-zero C (exact)
      float4v sacc[4][2];
      __builtin_amdgcn_s_setprio(1);
#pragma unroll
      for (int mt = 0; mt < 4; ++mt) {
        int key = sub64 + 16 * mt + ln;
        short8v kf = *(const short8v*)&Ks[key * 64 + ((qu ^ (key & 7)) * 8)];
        sacc[mt][0] = MFMA(kf, qf[0][0], zf);
        sacc[mt][1] = MFMA(kf, qf[1][0], zf);
      }
#pragma unroll
      for (int mt = 0; mt < 4; ++mt) {
        int key = sub64 + 16 * mt + ln;
        short8v kf = *(const short8v*)&Ks[key * 64 + (((4 + qu) ^ (key & 7)) * 8)];
        sacc[mt][0] = MFMA(kf, qf[0][1], sacc[mt][0]);
        sacc[mt][1] = MFMA(kf, qf[1][1], sacc[mt][1]);
      }
      __builtin_amdgcn_s_setprio(0);

      // per 32-key half: exp2 -> pack2r -> permlane transpose -> denom + PV
#pragma unroll
      for (int ks2 = 0; ks2 < 2; ++ks2) {
        short8v pf[2];
#pragma unroll
        for (int nt = 0; nt < 2; ++nt) {
          float4v s0v = sacc[2 * ks2][nt];      // mh=0: keys 16*2ks2 + 4qu + r
          float4v s1v = sacc[2 * ks2 + 1][nt];  // mh=1: keys 16*(2ks2+1)+4qu+r
          float a0 = __builtin_amdgcn_exp2f(s0v[0]);
          float a1 = __builtin_amdgcn_exp2f(s0v[1]);
          float a2 = __builtin_amdgcn_exp2f(s0v[2]);
          float a3 = __builtin_amdgcn_exp2f(s0v[3]);
          float b0 = __builtin_amdgcn_exp2f(s1v[0]);
          float b1 = __builtin_amdgcn_exp2f(s1v[1]);
          float b2 = __builtin_amdgcn_exp2f(s1v[2]);
          float b3 = __builtin_amdgcn_exp2f(s1v[3]);
          unsigned int m00 = pack2r(a0, a1);    // (mh0,p0)
          unsigned int m01 = pack2r(a2, a3);    // (mh0,p1)
          unsigned int m10 = pack2r(b0, b1);    // (mh1,p0)
          unsigned int m11 = pack2r(b2, b3);    // (mh1,p1)
          asm("v_permlane32_swap_b32 %0, %1" : "+v"(m00), "+v"(m10));
          asm("v_permlane32_swap_b32 %0, %1" : "+v"(m01), "+v"(m11));
          asm("v_permlane16_swap_b32 %0, %1" : "+v"(m00), "+v"(m10));
          asm("v_permlane16_swap_b32 %0, %1" : "+v"(m01), "+v"(m11));
          uint4v t; t[0] = m00; t[1] = m01; t[2] = m10; t[3] = m11;
          pf[nt] = __builtin_bit_cast(short8v, t);
        }
        __builtin_amdgcn_s_setprio(1);
#pragma unroll
        for (int nt = 0; nt < 2; ++nt)
          acc_l[nt] = MFMA(onesf, pf[nt], acc_l[nt]);   // row-sum of P
#pragma unroll
        for (int mt2 = 0; mt2 < 4; ++mt2) {
          int dd = 16 * mt2 + ln;
          short8v vf = *(const short8v*)&Vs[sub][dd * 64 + (((ks2 * 4 + qu) ^ (dd & 7)) * 8)];
#pragma unroll
          for (int nt = 0; nt < 2; ++nt)
            acc_o[mt2][nt] = MFMA(vf, pf[nt], acc_o[mt2][nt]);
        }
        __builtin_amdgcn_s_setprio(0);
      }
    }
  }

  float inv[2];
  inv[0] = 1.0f / acc_l[0][0];
  inv[1] = 1.0f / acc_l[1][0];
  unsigned short* Og = attnb + (size_t)((co * 8 + b)) * NCK * EMB + h * HD;
#pragma unroll
  for (int mt = 0; mt < 4; ++mt) {
    int dd0 = 16 * mt + 4 * qu;
#pragma unroll
    for (int nt = 0; nt < 2; ++nt) {
      int q_glob = q0 + w * 32 + nt * 16 + ln;
      ushort4v p;
#pragma unroll
      for (int r = 0; r < 4; ++r) p[r] = f2b(acc_o[mt][nt][r] * inv[nt]);
      *(ushort4v*)&Og[(size_t)q_glob * EMB + dd0] = p;
    }
  }
}

// ---------------- Output projection ----------------
// A = attnb (bf16), B = Wp_bf (bf16): both via global_load_lds, single-buffer.
// 1D grid 768, T1 XCD-chunk swizzle (VERIFIED R9): lin=(bid&7)*96+bid/8;
// col0=(lin&3)*128, row0=(lin>>2)*128 -> 4 attnb-panel sharers consecutive.
// D = Wp·A^T -> [f][token]; fp32 float4 stores.
__global__ __launch_bounds__(256) void proj_gemm(
    const unsigned short* __restrict__ attnb,
    const unsigned short* __restrict__ Wpb, const float* __restrict__ bp,
    float* __restrict__ out)
{
  const int tid = threadIdx.x;
  const int w = tid >> 6, l = tid & 63;
  const int ln = l & 15, qu = l >> 4;
  const int sr = l >> 3, kbl = l & 7;
  const int bid = blockIdx.x;
  const int lin = (bid & 7) * 96 + (bid >> 3);
  const int col0 = (lin & 3) * 128;
  const int row0 = (lin >> 2) * 128;          // [c][b][n] rows
  const int c = row0 >> 13;
  const int bglob = (row0 >> 10) & 7;
  const int n0 = row0 & 1023;
  const unsigned short* W = Wpb + c * EMB * EMB;
  const float* bias = bp + c * EMB;

  __shared__ unsigned short As[128 * 64];
  __shared__ unsigned short Bs[128 * 64];

  const int xo = (w & 1) * 64, fo = (w >> 1) * 64;

  float4v acc[4][4];
#pragma unroll
  for (int i = 0; i < 4; ++i)
#pragma unroll
    for (int j = 0; j < 4; ++j) acc[i][j] = (float4v){0.f, 0.f, 0.f, 0.f};

  for (int k0 = 0; k0 < EMB; k0 += 64) {
    __syncthreads();
#pragma unroll
    for (int s = 0; s < 4; ++s) {
      int rbase = w * 32 + s * 8;
      int r = rbase + sr;
      int kb_g = kbl ^ sr;
      gld_lds16(&attnb[(size_t)(row0 + r) * EMB + k0 + kb_g * 8], &As[rbase * 64]);
      gld_lds16(&W    [(size_t)(col0 + r) * EMB + k0 + kb_g * 8], &Bs[rbase * 64]);
    }
    __syncthreads();
#pragma unroll
    for (int ks = 0; ks < 2; ++ks) {
      short8v xf[4], wf[4];
#pragma unroll
      for (int i = 0; i < 4; ++i) {
        int rx = xo + 16 * i + ln;
        xf[i] = *(const short8v*)&As[rx * 64 + (((ks * 4 + qu) ^ (rx & 7)) * 8)];
        int rw = fo + 16 * i + ln;
        wf[i] = *(const short8v*)&Bs[rw * 64 + (((ks * 4 + qu) ^ (rw & 7)) * 8)];
      }
#pragma unroll
      for (int i = 0; i < 4; ++i)
#pragma unroll
        for (int j = 0; j < 4; ++j) acc[i][j] = MFMA(wf[j], xf[i], acc[i][j]);
    }
  }

#pragma unroll
  for (int j = 0; j < 4; ++j) {              // f (M side)
    int f0 = col0 + fo + 16 * j + 4 * qu;    // + r
    float4 b4 = *(const float4*)&bias[f0];
#pragma unroll
    for (int i = 0; i < 4; ++i) {            // token (N side)
      int srow = bglob * SEQ + c * NCK + n0 + xo + 16 * i + ln;
      float4 o;
      o.x = acc[i][j][0] + b4.x;
      o.y = acc[i][j][1] + b4.y;
      o.z = acc[i][j][2] + b4.z;
      o.w = acc[i][j][3] + b4.w;
      *(float4*)&out[(size_t)srow * EMB + f0] = o;
    }
  }
}

extern "C" void kernel_launch(void* const* d_in, const int* in_sizes, int n_in,
                              void* d_out, int out_size, void* d_ws, size_t ws_size,
                              hipStream_t stream) {
  (void)in_sizes; (void)n_in; (void)out_size; (void)ws_size;
  const float* x  = (const float*)d_in[0];
  const float* Wq = (const float*)d_in[1];
  const float* bq = (const float*)d_in[2];
  const float* Wk = (const float*)d_in[3];
  const float* bk = (const float*)d_in[4];
  const float* Wv = (const float*)d_in[5];
  const float* bv = (const float*)d_in[6];
  const float* Wp = (const float*)d_in[7];
  const float* bp = (const float*)d_in[8];
  float* out = (float*)d_out;

  // workspace layout (bf16 elems): [Wb 4*WELEMS][qt][kt][vt][attn(=x_bf)]
  // = 6.3 MB + 4*25.2 MB = 107 MB. x_bf aliases the attn slot: x_bf is only
  // read by qkv_gemm, which completes before attn_kernel writes attnb.
  unsigned short* Wb   = (unsigned short*)d_ws;
  unsigned short* qt   = Wb + 4 * (size_t)WELEMS;
  unsigned short* kt   = qt + QKV_ELEMS;
  unsigned short* vt   = kt + QKV_ELEMS;
  unsigned short* attn = vt + QKV_ELEMS;
  unsigned short* xbf  = attn;  // alias (see above)

  conv_all<<<XCONV_BLOCKS + 4 * WCONV_BLOCKS, 256, 0, stream>>>(
      x, Wq, Wk, Wv, Wp, xbf, Wb);
  qkv_gemm<<<(MTOT / 128) * (EMB / 128) * 3, 256, 0, stream>>>(
      xbf, Wb, bq, bk, bv, qt, kt, vt);
  attn_kernel<<<(NCK / 256) * CHUNKS * BATCH * NH, 512, 0, stream>>>(qt, kt, vt, attn);
  proj_gemm<<<(MTOT / 128) * (EMB / 128), 256, 0, stream>>>(attn, Wb + 3 * (size_t)WELEMS, bp, out);
}